// Round 3
// baseline (1177.726 us; speedup 1.0000x reference)
//
#include <hip/hip_runtime.h>
#include <math.h>

// Problem constants
#define BB 4
#define NN 8192
#define CC 64
#define KK 16
#define HH 64
#define NPTS (BB*NN)   // 32768
#define EPSBN 1e-5f

// ---------------- ws layout (float offsets) ----------------
#define OFF_XYZW  0
#define OFF_PW1AT 131072
#define OFF_PW1BT 135168
#define OFF_PWVAT 139264
#define OFF_PWOT  143360
#define OFF_RELW  147456
#define OFF_STATS 147840
#define OFF_IDX   148224
#define OFF_PDP   672512
#define OFF_PIP   1721088
#define OFF_F1    2769664
#define OFF_F2    4866816
#define OFF_FV    6963968
#define OFF_OPRE  9061120

__global__ __launch_bounds__(256) void k_prep(
    const float* __restrict__ xyz, const float* __restrict__ W1,
    const float* __restrict__ Wv, const float* __restrict__ Wo,
    float* __restrict__ xyzw, float* __restrict__ pw1aT, float* __restrict__ pw1bT,
    float* __restrict__ pwvaT, float* __restrict__ pwoT, float* __restrict__ relw,
    float* __restrict__ stats)
{
    int t = threadIdx.x;
    int bid = blockIdx.x;
    if (bid < 128) {
        int pt = bid * 256 + t;
        int b = pt >> 13, n = pt & 8191;
        const float* xb = xyz + (size_t)b * 3 * NN;
        float x = xb[n], y = xb[NN + n], z = xb[2 * NN + n];
        float sq = __fadd_rn(__fadd_rn(__fmul_rn(x, x), __fmul_rn(y, y)), __fmul_rn(z, z));
        ((float4*)xyzw)[pt] = make_float4(x, y, z, sq);
    } else {
        for (int e = t; e < 4096; e += 256) {
            int c = e >> 6, o = e & 63;
            pw1aT[e] = W1[o * 131 + c];
            pw1bT[e] = W1[o * 131 + 64 + c];
            pwvaT[e] = Wv[o * 67 + c];
            pwoT[e]  = Wo[o * 64 + c];
        }
        for (int e = t; e < 384; e += 256) {
            int d = e >> 6, o = e & 63;
            relw[e] = (d < 3) ? W1[o * 131 + 128 + d] : Wv[o * 67 + 64 + (d - 3)];
            stats[e] = 0.0f;
        }
    }
}

// Per-point GEMVs: F1 = b1 + W1a*feat, F2 = W1b*feat, FV = bv + Wva*feat
__global__ __launch_bounds__(256) void k_F(
    const float* __restrict__ feats, const float* __restrict__ b1, const float* __restrict__ bv,
    const float* __restrict__ pw1aT, const float* __restrict__ pw1bT, const float* __restrict__ pwvaT,
    float* __restrict__ F1, float* __restrict__ F2, float* __restrict__ FV)
{
    int t = threadIdx.x;
    int lane = t & 63;
    int wave = t >> 6;
    int pt0 = blockIdx.x * 64 + wave * 16;       // 16 points per wave
    int b   = __builtin_amdgcn_readfirstlane(pt0 >> 13);
    int n0  = __builtin_amdgcn_readfirstlane(pt0 & 8191);
    const float* fb = feats + (size_t)b * CC * NN;
    float accA[16], accB[16], accV[16];
    float bb1 = b1[lane], bbv = bv[lane];
#pragma unroll
    for (int p = 0; p < 16; p++) { accA[p] = bb1; accB[p] = 0.f; accV[p] = bbv; }
    for (int c = 0; c < 64; c++) {
        float wA = pw1aT[c * 64 + lane];
        float wB = pw1bT[c * 64 + lane];
        float wV = pwvaT[c * 64 + lane];
        const float* fr = fb + (size_t)c * NN + n0;   // uniform -> scalar loads
#pragma unroll
        for (int p = 0; p < 16; p++) {
            float f = fr[p];
            accA[p] = fmaf(wA, f, accA[p]);
            accB[p] = fmaf(wB, f, accB[p]);
            accV[p] = fmaf(wV, f, accV[p]);
        }
    }
#pragma unroll
    for (int p = 0; p < 16; p++) {
        int pt = pt0 + p;
        F1[(size_t)pt * 64 + lane] = accA[p];
        F2[(size_t)pt * 64 + lane] = accB[p];
        FV[(size_t)pt * 64 + lane] = accV[p];
    }
}

// Brute-force KNN pre-filter (fp32), candidates split in 2 halves, top-16 per half.
__global__ __launch_bounds__(256) void k_knn(
    const float4* __restrict__ xyzw, float* __restrict__ pdp, int* __restrict__ pip)
{
    int t = threadIdx.x;
    int pt = blockIdx.x * 256 + t;
    int half = blockIdx.y;
    int b = __builtin_amdgcn_readfirstlane(pt >> 13);
    float4 me = xyzw[pt];
    const float4* cb = xyzw + ((size_t)b << 13);
    int j0 = half * 4096, j1 = j0 + 4096;
    float bd[16]; int bi[16];
#pragma unroll
    for (int s = 0; s < 16; s++) { bd[s] = 3.402823466e38f; bi[s] = 0; }
#pragma unroll 2
    for (int j = j0; j < j1; j++) {
        float4 cj = cb[j];
        float dot = fmaf(me.z, cj.z, fmaf(me.y, cj.y, __fmul_rn(me.x, cj.x)));
        float d = __fadd_rn(fmaf(-2.f, dot, me.w), cj.w);
        if (d < bd[15]) {
            float pd_ = d; int pi_ = j;
#pragma unroll
            for (int s = 15; s >= 1; s--) {
                bool cc = pd_ < bd[s - 1];
                float nd = cc ? bd[s - 1] : pd_;  int ni = cc ? bi[s - 1] : pi_;
                float npd = cc ? pd_ : bd[s - 1]; int npi = cc ? pi_ : bi[s - 1];
                bd[s] = nd; bi[s] = ni; pd_ = npd; pi_ = npi;
            }
            bd[0] = pd_; bi[0] = pi_;
        }
    }
#pragma unroll
    for (int s = 0; s < 16; s++) {
        pdp[(size_t)(half * 16 + s) * NPTS + pt] = bd[s];
        pip[(size_t)(half * 16 + s) * NPTS + pt] = bi[s];
    }
}

// Exact refinement: recompute d for the 32 surviving candidates in fp64,
// select top-16 with lexicographic (d, index) tie-break.
// fp64 products of fp32 values are exact -> selection is summation-order
// independent to ~1e-15, matching any fp64 golden reference.
__global__ __launch_bounds__(256) void k_refine(
    const float4* __restrict__ xyzw, const int* __restrict__ pip, int* __restrict__ idx)
{
    int pt = blockIdx.x * 256 + threadIdx.x;
    int b = pt >> 13;
    const float4* cb = xyzw + ((size_t)b << 13);
    float4 mef = cb[pt & 8191];
    double mx = (double)mef.x, my = (double)mef.y, mz = (double)mef.z;
    double msq = (mx * mx + my * my) + mz * mz;
    double bd[16]; int bi[16];
#pragma unroll
    for (int s = 0; s < 16; s++) { bd[s] = 1e300; bi[s] = 0x7fffffff; }
    for (int c = 0; c < 32; c++) {
        int j = pip[(size_t)c * NPTS + pt];
        float4 cj = cb[j];
        double jx = (double)cj.x, jy = (double)cj.y, jz = (double)cj.z;
        double dot = (mx * jx + my * jy) + mz * jz;
        double sqj = (jx * jx + jy * jy) + jz * jz;
        double d = (-2.0 * dot + msq) + sqj;
        if (d < bd[15] || (d == bd[15] && j < bi[15])) {
            double pd_ = d; int pi_ = j;
#pragma unroll
            for (int s = 15; s >= 1; s--) {
                bool cc = (pd_ < bd[s - 1]) || (pd_ == bd[s - 1] && pi_ < bi[s - 1]);
                double nd = cc ? bd[s - 1] : pd_;  int ni = cc ? bi[s - 1] : pi_;
                double npd = cc ? pd_ : bd[s - 1]; int npi = cc ? pi_ : bi[s - 1];
                bd[s] = nd; bi[s] = ni; pd_ = npd; pi_ = npi;
            }
            bd[0] = pd_; bi[0] = pi_;
        }
    }
#pragma unroll
    for (int s = 0; s < 16; s++) idx[(size_t)pt * 16 + s] = bi[s];
}

// Pass over all (pt,k): pre-BN h and v, accumulate per-channel sum/sumsq.
__global__ __launch_bounds__(256) void k_hv(
    const float4* __restrict__ xyzw, const int* __restrict__ idx,
    const float* __restrict__ F1, const float* __restrict__ F2, const float* __restrict__ FV,
    const float* __restrict__ relw, float* __restrict__ stats)
{
    int t = threadIdx.x;
    int lane = t & 63;
    int w = blockIdx.x * 4 + (t >> 6);   // 0..4095
    float rw0 = relw[0 * 64 + lane], rw1 = relw[1 * 64 + lane], rw2 = relw[2 * 64 + lane];
    float rw3 = relw[3 * 64 + lane], rw4 = relw[4 * 64 + lane], rw5 = relw[5 * 64 + lane];
    float sh = 0.f, sh2 = 0.f, sv = 0.f, sv2 = 0.f;
    for (int i = 0; i < 8; i++) {
        int ptu = __builtin_amdgcn_readfirstlane(w + i * 4096);
        int b = ptu >> 13;
        float4 me = xyzw[ptu];
        float F1v = F1[(size_t)ptu * 64 + lane];
        const int* ip = idx + (size_t)ptu * 16;
#pragma unroll
        for (int k = 0; k < 16; k++) {
            int g = (b << 13) + ip[k];
            float4 cj = xyzw[g];
            float rx = cj.x - me.x, ry = cj.y - me.y, rz = cj.z - me.z;
            float h = F1v + F2[(size_t)g * 64 + lane];
            h = fmaf(rw0, rx, h); h = fmaf(rw1, ry, h); h = fmaf(rw2, rz, h);
            float v = FV[(size_t)g * 64 + lane];
            v = fmaf(rw3, rx, v); v = fmaf(rw4, ry, v); v = fmaf(rw5, rz, v);
            sh += h; sh2 = fmaf(h, h, sh2);
            sv += v; sv2 = fmaf(v, v, sv2);
        }
    }
    atomicAdd(&stats[lane], sh);       atomicAdd(&stats[64 + lane], sh2);
    atomicAdd(&stats[128 + lane], sv); atomicAdd(&stats[192 + lane], sv2);
}

// Attention: BN(h)+relu -> logits -> softmax -> BN(v)+relu weighted sum -> Wo matvec -> o_pre + o stats
__global__ __launch_bounds__(256) void k_attn(
    const float4* __restrict__ xyzw, const int* __restrict__ idx,
    const float* __restrict__ F1, const float* __restrict__ F2, const float* __restrict__ FV,
    const float* __restrict__ relw, float* __restrict__ stats,
    const float* __restrict__ g1, const float* __restrict__ be1,
    const float* __restrict__ W2, const float* __restrict__ b2,
    const float* __restrict__ gv, const float* __restrict__ bev,
    const float* __restrict__ pwoT, const float* __restrict__ bo,
    float* __restrict__ opre)
{
    int t = threadIdx.x;
    int lane = t & 63;
    int wl = t >> 6;
    int w = blockIdx.x * 4 + wl;   // 0..8191
    const float invM = 1.f / 524288.f;
    float hm = stats[lane] * invM, hq = stats[64 + lane] * invM;
    float s1 = g1[lane] * rsqrtf(hq - hm * hm + EPSBN);
    float t1 = be1[lane] - s1 * hm;
    float vm = stats[128 + lane] * invM, vq = stats[192 + lane] * invM;
    float sv = gv[lane] * rsqrtf(vq - vm * vm + EPSBN);
    float tv = bev[lane] - sv * vm;
    float rw0 = relw[0 * 64 + lane], rw1 = relw[1 * 64 + lane], rw2 = relw[2 * 64 + lane];
    float rw3 = relw[3 * 64 + lane], rw4 = relw[4 * 64 + lane], rw5 = relw[5 * 64 + lane];
    float w2v = W2[lane];
    float b2v = b2[0];
    float bov = bo[lane];
    float so_ = 0.f, so2 = 0.f;
    __shared__ float lds_out[4][64];

    for (int i = 0; i < 4; i++) {
        int ptu = __builtin_amdgcn_readfirstlane(w + i * 8192);
        int b = ptu >> 13;
        float4 me = xyzw[ptu];
        float F1v = F1[(size_t)ptu * 64 + lane];
        const int* ip = idx + (size_t)ptu * 16;
        float ek[16], vk[16];
#pragma unroll
        for (int k = 0; k < 16; k++) {
            int g = (b << 13) + ip[k];
            float4 cj = xyzw[g];
            float rx = cj.x - me.x, ry = cj.y - me.y, rz = cj.z - me.z;
            float h = F1v + F2[(size_t)g * 64 + lane];
            h = fmaf(rw0, rx, h); h = fmaf(rw1, ry, h); h = fmaf(rw2, rz, h);
            float a = fmaxf(fmaf(s1, h, t1), 0.f);
            float v = FV[(size_t)g * 64 + lane];
            v = fmaf(rw3, rx, v); v = fmaf(rw4, ry, v); v = fmaf(rw5, rz, v);
            vk[k] = fmaxf(fmaf(sv, v, tv), 0.f);
            float lg = w2v * a;
#pragma unroll
            for (int off = 32; off >= 1; off >>= 1) lg += __shfl_xor(lg, off, 64);
            ek[k] = lg + b2v;
        }
        float mx = ek[0];
#pragma unroll
        for (int k = 1; k < 16; k++) mx = fmaxf(mx, ek[k]);
        float ssum = 0.f;
#pragma unroll
        for (int k = 0; k < 16; k++) { float e = __expf(ek[k] - mx); ek[k] = e; ssum += e; }
        float acc = 0.f;
#pragma unroll
        for (int k = 0; k < 16; k++) acc = fmaf(ek[k], vk[k], acc);
        float outv = acc / ssum;

        lds_out[wl][lane] = outv;
        __syncthreads();
        float op = bov;
        for (int c = 0; c < 64; c++)
            op = fmaf(pwoT[c * 64 + lane], lds_out[wl][c], op);
        opre[(size_t)ptu * 64 + lane] = op;
        so_ += op; so2 = fmaf(op, op, so2);
        __syncthreads();
    }
    atomicAdd(&stats[256 + lane], so_);
    atomicAdd(&stats[320 + lane], so2);
}

// Final: BN(o)+relu + residual feats, transpose [B,N,C]->[B,C,N]
__global__ __launch_bounds__(256) void k_final(
    const float* __restrict__ opre, const float* __restrict__ stats,
    const float* __restrict__ go, const float* __restrict__ beo,
    const float* __restrict__ feats, float* __restrict__ out)
{
    __shared__ float tile[64][65];
    int t = threadIdx.x;
    int blk = blockIdx.x;
    int b = blk >> 7, n0 = (blk & 127) << 6;
#pragma unroll
    for (int i = 0; i < 16; i++) {
        int e = t + i * 256;
        int r = e >> 6, c = e & 63;
        tile[r][c] = opre[((size_t)((b << 13) + n0 + r)) * 64 + c];
    }
    __syncthreads();
    const float invM = 1.f / 32768.f;
    int lane = t & 63, wv = t >> 6;
#pragma unroll
    for (int i = 0; i < 16; i++) {
        int c = wv * 16 + i;
        float om = stats[256 + c] * invM, oq = stats[320 + c] * invM;
        float so = go[c] * rsqrtf(oq - om * om + EPSBN);
        float to = beo[c] - so * om;
        float val = fmaxf(fmaf(so, tile[lane][c], to), 0.f);
        size_t oix = ((size_t)b * 64 + c) * NN + n0 + lane;
        out[oix] = val + feats[oix];
    }
}

extern "C" void kernel_launch(void* const* d_in, const int* in_sizes, int n_in,
                              void* d_out, int out_size, void* d_ws, size_t ws_size,
                              hipStream_t stream)
{
    const float* xyz  = (const float*)d_in[0];
    const float* feats= (const float*)d_in[1];
    const float* W1   = (const float*)d_in[2];
    const float* b1   = (const float*)d_in[3];
    const float* g1   = (const float*)d_in[4];
    const float* be1  = (const float*)d_in[5];
    const float* W2   = (const float*)d_in[6];
    const float* b2   = (const float*)d_in[7];
    const float* Wv   = (const float*)d_in[8];
    const float* bv   = (const float*)d_in[9];
    const float* gv   = (const float*)d_in[10];
    const float* bev  = (const float*)d_in[11];
    const float* Wo   = (const float*)d_in[12];
    const float* bo   = (const float*)d_in[13];
    const float* go   = (const float*)d_in[14];
    const float* beo  = (const float*)d_in[15];

    float* ws = (float*)d_ws;
    float* xyzw  = ws + OFF_XYZW;
    float* pw1aT = ws + OFF_PW1AT;
    float* pw1bT = ws + OFF_PW1BT;
    float* pwvaT = ws + OFF_PWVAT;
    float* pwoT  = ws + OFF_PWOT;
    float* relw  = ws + OFF_RELW;
    float* stats = ws + OFF_STATS;
    int*   idx   = (int*)(ws + OFF_IDX);
    float* pdp   = ws + OFF_PDP;
    int*   pip   = (int*)(ws + OFF_PIP);
    float* F1    = ws + OFF_F1;
    float* F2    = ws + OFF_F2;
    float* FV    = ws + OFF_FV;
    float* opre  = ws + OFF_OPRE;

    k_prep<<<129, 256, 0, stream>>>(xyz, W1, Wv, Wo, xyzw, pw1aT, pw1bT, pwvaT, pwoT, relw, stats);
    k_F<<<512, 256, 0, stream>>>(feats, b1, bv, pw1aT, pw1bT, pwvaT, F1, F2, FV);
    k_knn<<<dim3(128, 2), 256, 0, stream>>>((const float4*)xyzw, pdp, pip);
    k_refine<<<128, 256, 0, stream>>>((const float4*)xyzw, pip, idx);
    k_hv<<<1024, 256, 0, stream>>>((const float4*)xyzw, idx, F1, F2, FV, relw, stats);
    k_attn<<<2048, 256, 0, stream>>>((const float4*)xyzw, idx, F1, F2, FV, relw, stats,
                                     g1, be1, W2, b2, gv, bev, pwoT, bo, opre);
    k_final<<<512, 256, 0, stream>>>(opre, stats, go, beo, feats, (float*)d_out);
}

// Round 4
// 1085.986 us; speedup vs baseline: 1.0845x; 1.0845x over previous
//
#include <hip/hip_runtime.h>
#include <math.h>

// Problem constants
#define BB 4
#define NN 8192
#define CC 64
#define KK 16
#define HH 64
#define NPTS (BB*NN)   // 32768
#define EPSBN 1e-5f
#define NSEG 8
#define SEGLEN (NN/NSEG)   // 1024

// ---------------- ws layout (float offsets) ----------------
// XYZW [32768][4]; packed weights; STATS[6][64]; IDX[32768][16] int;
// PIP [NSEG*16][32768] int (dead after k_refine; OPRE aliases it);
// F1/F2/FV [32768][64]. High-water = 11,158,272 floats = 44.6 MB (proven fit).
#define OFF_XYZW  0
#define OFF_PW1AT 131072
#define OFF_PW1BT 135168
#define OFF_PWVAT 139264
#define OFF_PWOT  143360
#define OFF_RELW  147456
#define OFF_STATS 147840
#define OFF_IDX   148224
#define OFF_PIP   672512
#define OFF_OPRE  672512      // aliases PIP (PIP dead after k_refine; OPRE written in k_attn)
#define OFF_F1    4866816
#define OFF_F2    6963968
#define OFF_FV    9061120

__global__ __launch_bounds__(256) void k_prep(
    const float* __restrict__ xyz, const float* __restrict__ W1,
    const float* __restrict__ Wv, const float* __restrict__ Wo,
    float* __restrict__ xyzw, float* __restrict__ pw1aT, float* __restrict__ pw1bT,
    float* __restrict__ pwvaT, float* __restrict__ pwoT, float* __restrict__ relw,
    float* __restrict__ stats)
{
    int t = threadIdx.x;
    int bid = blockIdx.x;
    if (bid < 128) {
        int pt = bid * 256 + t;
        int b = pt >> 13, n = pt & 8191;
        const float* xb = xyz + (size_t)b * 3 * NN;
        float x = xb[n], y = xb[NN + n], z = xb[2 * NN + n];
        float sq = __fadd_rn(__fadd_rn(__fmul_rn(x, x), __fmul_rn(y, y)), __fmul_rn(z, z));
        ((float4*)xyzw)[pt] = make_float4(x, y, z, sq);
    } else {
        for (int e = t; e < 4096; e += 256) {
            int c = e >> 6, o = e & 63;
            pw1aT[e] = W1[o * 131 + c];
            pw1bT[e] = W1[o * 131 + 64 + c];
            pwvaT[e] = Wv[o * 67 + c];
            pwoT[e]  = Wo[o * 64 + c];
        }
        for (int e = t; e < 384; e += 256) {
            int d = e >> 6, o = e & 63;
            relw[e] = (d < 3) ? W1[o * 131 + 128 + d] : Wv[o * 67 + 64 + (d - 3)];
            stats[e] = 0.0f;
        }
    }
}

// Per-point GEMVs: F1 = b1 + W1a*feat, F2 = W1b*feat, FV = bv + Wva*feat
__global__ __launch_bounds__(256) void k_F(
    const float* __restrict__ feats, const float* __restrict__ b1, const float* __restrict__ bv,
    const float* __restrict__ pw1aT, const float* __restrict__ pw1bT, const float* __restrict__ pwvaT,
    float* __restrict__ F1, float* __restrict__ F2, float* __restrict__ FV)
{
    int t = threadIdx.x;
    int lane = t & 63;
    int wave = t >> 6;
    int pt0 = blockIdx.x * 64 + wave * 16;       // 16 points per wave
    int b   = __builtin_amdgcn_readfirstlane(pt0 >> 13);
    int n0  = __builtin_amdgcn_readfirstlane(pt0 & 8191);
    const float* fb = feats + (size_t)b * CC * NN;
    float accA[16], accB[16], accV[16];
    float bb1 = b1[lane], bbv = bv[lane];
#pragma unroll
    for (int p = 0; p < 16; p++) { accA[p] = bb1; accB[p] = 0.f; accV[p] = bbv; }
    for (int c = 0; c < 64; c++) {
        float wA = pw1aT[c * 64 + lane];
        float wB = pw1bT[c * 64 + lane];
        float wV = pwvaT[c * 64 + lane];
        const float* fr = fb + (size_t)c * NN + n0;   // uniform -> scalar loads
#pragma unroll
        for (int p = 0; p < 16; p++) {
            float f = fr[p];
            accA[p] = fmaf(wA, f, accA[p]);
            accB[p] = fmaf(wB, f, accB[p]);
            accV[p] = fmaf(wV, f, accV[p]);
        }
    }
#pragma unroll
    for (int p = 0; p < 16; p++) {
        int pt = pt0 + p;
        F1[(size_t)pt * 64 + lane] = accA[p];
        F2[(size_t)pt * 64 + lane] = accB[p];
        FV[(size_t)pt * 64 + lane] = accV[p];
    }
}

// Brute-force KNN pre-filter (fp32), candidates split in NSEG segments,
// top-16 per segment; only indices stored (fp64 refine recomputes distances).
__global__ __launch_bounds__(256) void k_knn(
    const float4* __restrict__ xyzw, int* __restrict__ pip)
{
    int t = threadIdx.x;
    int pt = blockIdx.x * 256 + t;
    int seg = blockIdx.y;
    int b = __builtin_amdgcn_readfirstlane(pt >> 13);
    float4 me = xyzw[pt];
    const float4* cb = xyzw + ((size_t)b << 13);
    int j0 = seg * SEGLEN, j1 = j0 + SEGLEN;
    float bd[16]; int bi[16];
#pragma unroll
    for (int s = 0; s < 16; s++) { bd[s] = 3.402823466e38f; bi[s] = 0; }
#pragma unroll 2
    for (int j = j0; j < j1; j++) {
        float4 cj = cb[j];   // wave-uniform -> s_load
        float dot = fmaf(me.z, cj.z, fmaf(me.y, cj.y, __fmul_rn(me.x, cj.x)));
        float d = __fadd_rn(fmaf(-2.f, dot, me.w), cj.w);
        if (d < bd[15]) {
            float pd_ = d; int pi_ = j;
#pragma unroll
            for (int s = 15; s >= 1; s--) {
                bool cc = pd_ < bd[s - 1];
                float nd = cc ? bd[s - 1] : pd_;  int ni = cc ? bi[s - 1] : pi_;
                float npd = cc ? pd_ : bd[s - 1]; int npi = cc ? pi_ : bi[s - 1];
                bd[s] = nd; bi[s] = ni; pd_ = npd; pi_ = npi;
            }
            bd[0] = pd_; bi[0] = pi_;
        }
    }
#pragma unroll
    for (int s = 0; s < 16; s++)
        pip[(size_t)(seg * 16 + s) * NPTS + pt] = bi[s];
}

// Exact refinement: recompute d for the NSEG*16 surviving candidates in fp64,
// select top-16 with lexicographic (d, index) tie-break.
// fp64 products of fp32 values are exact -> selection matches any fp64 golden ref.
__global__ __launch_bounds__(256) void k_refine(
    const float4* __restrict__ xyzw, const int* __restrict__ pip, int* __restrict__ idx)
{
    int pt = blockIdx.x * 256 + threadIdx.x;
    int b = pt >> 13;
    const float4* cb = xyzw + ((size_t)b << 13);
    float4 mef = cb[pt & 8191];
    double mx = (double)mef.x, my = (double)mef.y, mz = (double)mef.z;
    double msq = (mx * mx + my * my) + mz * mz;
    double bd[16]; int bi[16];
#pragma unroll
    for (int s = 0; s < 16; s++) { bd[s] = 1e300; bi[s] = 0x7fffffff; }
    for (int c = 0; c < NSEG * 16; c++) {
        int j = pip[(size_t)c * NPTS + pt];
        float4 cj = cb[j];
        double jx = (double)cj.x, jy = (double)cj.y, jz = (double)cj.z;
        double dot = (mx * jx + my * jy) + mz * jz;
        double sqj = (jx * jx + jy * jy) + jz * jz;
        double d = (-2.0 * dot + msq) + sqj;
        if (d < bd[15] || (d == bd[15] && j < bi[15])) {
            double pd_ = d; int pi_ = j;
#pragma unroll
            for (int s = 15; s >= 1; s--) {
                bool cc = (pd_ < bd[s - 1]) || (pd_ == bd[s - 1] && pi_ < bi[s - 1]);
                double nd = cc ? bd[s - 1] : pd_;  int ni = cc ? bi[s - 1] : pi_;
                double npd = cc ? pd_ : bd[s - 1]; int npi = cc ? pi_ : bi[s - 1];
                bd[s] = nd; bi[s] = ni; pd_ = npd; pi_ = npi;
            }
            bd[0] = pd_; bi[0] = pi_;
        }
    }
#pragma unroll
    for (int s = 0; s < 16; s++) idx[(size_t)pt * 16 + s] = bi[s];
}

// Pass over all (pt,k): pre-BN h and v, accumulate per-channel sum/sumsq.
__global__ __launch_bounds__(256) void k_hv(
    const float4* __restrict__ xyzw, const int* __restrict__ idx,
    const float* __restrict__ F1, const float* __restrict__ F2, const float* __restrict__ FV,
    const float* __restrict__ relw, float* __restrict__ stats)
{
    int t = threadIdx.x;
    int lane = t & 63;
    int w = blockIdx.x * 4 + (t >> 6);   // 0..4095
    float rw0 = relw[0 * 64 + lane], rw1 = relw[1 * 64 + lane], rw2 = relw[2 * 64 + lane];
    float rw3 = relw[3 * 64 + lane], rw4 = relw[4 * 64 + lane], rw5 = relw[5 * 64 + lane];
    float sh = 0.f, sh2 = 0.f, sv = 0.f, sv2 = 0.f;
    for (int i = 0; i < 8; i++) {
        int ptu = __builtin_amdgcn_readfirstlane(w + i * 4096);
        int b = ptu >> 13;
        float4 me = xyzw[ptu];
        float F1v = F1[(size_t)ptu * 64 + lane];
        const int* ip = idx + (size_t)ptu * 16;
#pragma unroll
        for (int k = 0; k < 16; k++) {
            int g = (b << 13) + ip[k];
            float4 cj = xyzw[g];
            float rx = cj.x - me.x, ry = cj.y - me.y, rz = cj.z - me.z;
            float h = F1v + F2[(size_t)g * 64 + lane];
            h = fmaf(rw0, rx, h); h = fmaf(rw1, ry, h); h = fmaf(rw2, rz, h);
            float v = FV[(size_t)g * 64 + lane];
            v = fmaf(rw3, rx, v); v = fmaf(rw4, ry, v); v = fmaf(rw5, rz, v);
            sh += h; sh2 = fmaf(h, h, sh2);
            sv += v; sv2 = fmaf(v, v, sv2);
        }
    }
    atomicAdd(&stats[lane], sh);       atomicAdd(&stats[64 + lane], sh2);
    atomicAdd(&stats[128 + lane], sv); atomicAdd(&stats[192 + lane], sv2);
}

// Attention: BN(h)+relu -> logits -> softmax -> BN(v)+relu weighted sum -> Wo matvec -> o_pre + o stats
__global__ __launch_bounds__(256) void k_attn(
    const float4* __restrict__ xyzw, const int* __restrict__ idx,
    const float* __restrict__ F1, const float* __restrict__ F2, const float* __restrict__ FV,
    const float* __restrict__ relw, float* __restrict__ stats,
    const float* __restrict__ g1, const float* __restrict__ be1,
    const float* __restrict__ W2, const float* __restrict__ b2,
    const float* __restrict__ gv, const float* __restrict__ bev,
    const float* __restrict__ pwoT, const float* __restrict__ bo,
    float* __restrict__ opre)
{
    int t = threadIdx.x;
    int lane = t & 63;
    int wl = t >> 6;
    int w = blockIdx.x * 4 + wl;   // 0..8191
    const float invM = 1.f / 524288.f;
    float hm = stats[lane] * invM, hq = stats[64 + lane] * invM;
    float s1 = g1[lane] * rsqrtf(hq - hm * hm + EPSBN);
    float t1 = be1[lane] - s1 * hm;
    float vm = stats[128 + lane] * invM, vq = stats[192 + lane] * invM;
    float sv = gv[lane] * rsqrtf(vq - vm * vm + EPSBN);
    float tv = bev[lane] - sv * vm;
    float rw0 = relw[0 * 64 + lane], rw1 = relw[1 * 64 + lane], rw2 = relw[2 * 64 + lane];
    float rw3 = relw[3 * 64 + lane], rw4 = relw[4 * 64 + lane], rw5 = relw[5 * 64 + lane];
    float w2v = W2[lane];
    float b2v = b2[0];
    float bov = bo[lane];
    float so_ = 0.f, so2 = 0.f;
    __shared__ float lds_out[4][64];

    for (int i = 0; i < 4; i++) {
        int ptu = __builtin_amdgcn_readfirstlane(w + i * 8192);
        int b = ptu >> 13;
        float4 me = xyzw[ptu];
        float F1v = F1[(size_t)ptu * 64 + lane];
        const int* ip = idx + (size_t)ptu * 16;
        float ek[16], vk[16];
#pragma unroll
        for (int k = 0; k < 16; k++) {
            int g = (b << 13) + ip[k];
            float4 cj = xyzw[g];
            float rx = cj.x - me.x, ry = cj.y - me.y, rz = cj.z - me.z;
            float h = F1v + F2[(size_t)g * 64 + lane];
            h = fmaf(rw0, rx, h); h = fmaf(rw1, ry, h); h = fmaf(rw2, rz, h);
            float a = fmaxf(fmaf(s1, h, t1), 0.f);
            float v = FV[(size_t)g * 64 + lane];
            v = fmaf(rw3, rx, v); v = fmaf(rw4, ry, v); v = fmaf(rw5, rz, v);
            vk[k] = fmaxf(fmaf(sv, v, tv), 0.f);
            float lg = w2v * a;
#pragma unroll
            for (int off = 32; off >= 1; off >>= 1) lg += __shfl_xor(lg, off, 64);
            ek[k] = lg + b2v;
        }
        float mx = ek[0];
#pragma unroll
        for (int k = 1; k < 16; k++) mx = fmaxf(mx, ek[k]);
        float ssum = 0.f;
#pragma unroll
        for (int k = 0; k < 16; k++) { float e = __expf(ek[k] - mx); ek[k] = e; ssum += e; }
        float acc = 0.f;
#pragma unroll
        for (int k = 0; k < 16; k++) acc = fmaf(ek[k], vk[k], acc);
        float outv = acc / ssum;

        lds_out[wl][lane] = outv;
        __syncthreads();
        float op = bov;
        for (int c = 0; c < 64; c++)
            op = fmaf(pwoT[c * 64 + lane], lds_out[wl][c], op);
        opre[(size_t)ptu * 64 + lane] = op;
        so_ += op; so2 = fmaf(op, op, so2);
        __syncthreads();
    }
    atomicAdd(&stats[256 + lane], so_);
    atomicAdd(&stats[320 + lane], so2);
}

// Final: BN(o)+relu + residual feats, transpose [B,N,C]->[B,C,N]
__global__ __launch_bounds__(256) void k_final(
    const float* __restrict__ opre, const float* __restrict__ stats,
    const float* __restrict__ go, const float* __restrict__ beo,
    const float* __restrict__ feats, float* __restrict__ out)
{
    __shared__ float tile[64][65];
    int t = threadIdx.x;
    int blk = blockIdx.x;
    int b = blk >> 7, n0 = (blk & 127) << 6;
#pragma unroll
    for (int i = 0; i < 16; i++) {
        int e = t + i * 256;
        int r = e >> 6, c = e & 63;
        tile[r][c] = opre[((size_t)((b << 13) + n0 + r)) * 64 + c];
    }
    __syncthreads();
    const float invM = 1.f / 32768.f;
    int lane = t & 63, wv = t >> 6;
#pragma unroll
    for (int i = 0; i < 16; i++) {
        int c = wv * 16 + i;
        float om = stats[256 + c] * invM, oq = stats[320 + c] * invM;
        float so = go[c] * rsqrtf(oq - om * om + EPSBN);
        float to = beo[c] - so * om;
        float val = fmaxf(fmaf(so, tile[lane][c], to), 0.f);
        size_t oix = ((size_t)b * 64 + c) * NN + n0 + lane;
        out[oix] = val + feats[oix];
    }
}

extern "C" void kernel_launch(void* const* d_in, const int* in_sizes, int n_in,
                              void* d_out, int out_size, void* d_ws, size_t ws_size,
                              hipStream_t stream)
{
    const float* xyz  = (const float*)d_in[0];
    const float* feats= (const float*)d_in[1];
    const float* W1   = (const float*)d_in[2];
    const float* b1   = (const float*)d_in[3];
    const float* g1   = (const float*)d_in[4];
    const float* be1  = (const float*)d_in[5];
    const float* W2   = (const float*)d_in[6];
    const float* b2   = (const float*)d_in[7];
    const float* Wv   = (const float*)d_in[8];
    const float* bv   = (const float*)d_in[9];
    const float* gv   = (const float*)d_in[10];
    const float* bev  = (const float*)d_in[11];
    const float* Wo   = (const float*)d_in[12];
    const float* bo   = (const float*)d_in[13];
    const float* go   = (const float*)d_in[14];
    const float* beo  = (const float*)d_in[15];

    float* ws = (float*)d_ws;
    float* xyzw  = ws + OFF_XYZW;
    float* pw1aT = ws + OFF_PW1AT;
    float* pw1bT = ws + OFF_PW1BT;
    float* pwvaT = ws + OFF_PWVAT;
    float* pwoT  = ws + OFF_PWOT;
    float* relw  = ws + OFF_RELW;
    float* stats = ws + OFF_STATS;
    int*   idx   = (int*)(ws + OFF_IDX);
    int*   pip   = (int*)(ws + OFF_PIP);
    float* F1    = ws + OFF_F1;
    float* F2    = ws + OFF_F2;
    float* FV    = ws + OFF_FV;
    float* opre  = ws + OFF_OPRE;   // aliases pip (dead after k_refine)

    k_prep<<<129, 256, 0, stream>>>(xyz, W1, Wv, Wo, xyzw, pw1aT, pw1bT, pwvaT, pwoT, relw, stats);
    k_F<<<512, 256, 0, stream>>>(feats, b1, bv, pw1aT, pw1bT, pwvaT, F1, F2, FV);
    k_knn<<<dim3(128, NSEG), 256, 0, stream>>>((const float4*)xyzw, pip);
    k_refine<<<128, 256, 0, stream>>>((const float4*)xyzw, pip, idx);
    k_hv<<<1024, 256, 0, stream>>>((const float4*)xyzw, idx, F1, F2, FV, relw, stats);
    k_attn<<<2048, 256, 0, stream>>>((const float4*)xyzw, idx, F1, F2, FV, relw, stats,
                                     g1, be1, W2, b2, gv, bev, pwoT, bo, opre);
    k_final<<<512, 256, 0, stream>>>(opre, stats, go, beo, feats, (float*)d_out);
}

// Round 5
// 766.213 us; speedup vs baseline: 1.5371x; 1.4173x over previous
//
#include <hip/hip_runtime.h>
#include <math.h>

// Problem constants
#define BB 4
#define NN 8192
#define CC 64
#define KK 16
#define HH 64
#define NPTS (BB*NN)   // 32768
#define EPSBN 1e-5f
#define NCAND 32       // fp32 prefilter keeps top-32 per query; fp64 refine picks 16

// ---------------- ws layout (float offsets) ----------------
// XYZW [32768][4]; packed weights; STATS[6][64]; IDX[32768][16] int;
// PIP [32768][32] int (dead after k_refine; OPRE aliases region);
// F1/F2/FV [32768][64].
#define OFF_XYZW  0
#define OFF_PW1AT 131072
#define OFF_PW1BT 135168
#define OFF_PWVAT 139264
#define OFF_PWOT  143360
#define OFF_RELW  147456
#define OFF_STATS 147840
#define OFF_IDX   148224
#define OFF_PIP   672512
#define OFF_OPRE  672512      // aliases PIP (PIP dead after k_refine; OPRE written in k_attn)
#define OFF_F1    4866816
#define OFF_F2    6963968
#define OFF_FV    9061120

__global__ __launch_bounds__(256) void k_prep(
    const float* __restrict__ xyz, const float* __restrict__ W1,
    const float* __restrict__ Wv, const float* __restrict__ Wo,
    float* __restrict__ xyzw, float* __restrict__ pw1aT, float* __restrict__ pw1bT,
    float* __restrict__ pwvaT, float* __restrict__ pwoT, float* __restrict__ relw,
    float* __restrict__ stats)
{
    int t = threadIdx.x;
    int bid = blockIdx.x;
    if (bid < 128) {
        int pt = bid * 256 + t;
        int b = pt >> 13, n = pt & 8191;
        const float* xb = xyz + (size_t)b * 3 * NN;
        float x = xb[n], y = xb[NN + n], z = xb[2 * NN + n];
        float sq = __fadd_rn(__fadd_rn(__fmul_rn(x, x), __fmul_rn(y, y)), __fmul_rn(z, z));
        ((float4*)xyzw)[pt] = make_float4(x, y, z, sq);
    } else {
        for (int e = t; e < 4096; e += 256) {
            int c = e >> 6, o = e & 63;
            pw1aT[e] = W1[o * 131 + c];
            pw1bT[e] = W1[o * 131 + 64 + c];
            pwvaT[e] = Wv[o * 67 + c];
            pwoT[e]  = Wo[o * 64 + c];
        }
        for (int e = t; e < 384; e += 256) {
            int d = e >> 6, o = e & 63;
            relw[e] = (d < 3) ? W1[o * 131 + 128 + d] : Wv[o * 67 + 64 + (d - 3)];
            stats[e] = 0.0f;
        }
    }
}

// Per-point GEMVs: F1 = b1 + W1a*feat, F2 = W1b*feat, FV = bv + Wva*feat
__global__ __launch_bounds__(256) void k_F(
    const float* __restrict__ feats, const float* __restrict__ b1, const float* __restrict__ bv,
    const float* __restrict__ pw1aT, const float* __restrict__ pw1bT, const float* __restrict__ pwvaT,
    float* __restrict__ F1, float* __restrict__ F2, float* __restrict__ FV)
{
    int t = threadIdx.x;
    int lane = t & 63;
    int wave = t >> 6;
    int pt0 = blockIdx.x * 64 + wave * 16;       // 16 points per wave
    int b   = __builtin_amdgcn_readfirstlane(pt0 >> 13);
    int n0  = __builtin_amdgcn_readfirstlane(pt0 & 8191);
    const float* fb = feats + (size_t)b * CC * NN;
    float accA[16], accB[16], accV[16];
    float bb1 = b1[lane], bbv = bv[lane];
#pragma unroll
    for (int p = 0; p < 16; p++) { accA[p] = bb1; accB[p] = 0.f; accV[p] = bbv; }
    for (int c = 0; c < 64; c++) {
        float wA = pw1aT[c * 64 + lane];
        float wB = pw1bT[c * 64 + lane];
        float wV = pwvaT[c * 64 + lane];
        const float* fr = fb + (size_t)c * NN + n0;   // uniform -> scalar loads
#pragma unroll
        for (int p = 0; p < 16; p++) {
            float f = fr[p];
            accA[p] = fmaf(wA, f, accA[p]);
            accB[p] = fmaf(wB, f, accB[p]);
            accV[p] = fmaf(wV, f, accV[p]);
        }
    }
#pragma unroll
    for (int p = 0; p < 16; p++) {
        int pt = pt0 + p;
        F1[(size_t)pt * 64 + lane] = accA[p];
        F2[(size_t)pt * 64 + lane] = accB[p];
        FV[(size_t)pt * 64 + lane] = accV[p];
    }
}

// Wave-cooperative KNN prefilter: ONE query per wave, 64 candidates/step.
// Sorted top-32 held one-entry-per-lane in lanes 0..31 (ascending), scalar
// threshold tau = 32nd best. Insert cost paid only on actual hits
// (~205/query vs 8192 candidates). Candidates staged via 16KB SoA LDS.
__global__ __launch_bounds__(256) void k_knn(
    const float4* __restrict__ xyzw, int* __restrict__ pip)
{
    __shared__ float lx[1024], ly[1024], lz[1024], lw[1024];
    int t = threadIdx.x;
    int lane = t & 63;
    int wl = t >> 6;
    int pt = blockIdx.x * 4 + wl;                 // one query per wave
    int b = __builtin_amdgcn_readfirstlane(pt >> 13);
    const float4* cb = xyzw + ((size_t)b << 13);
    float4 me = cb[pt & 8191];                    // uniform -> scalar load
    const float INF = 3.402823466e38f;
    float val = INF;  int vid = 0;                // lanes 0..31: sorted list
    float tau = INF;
    bool lt32 = (lane < 32);

    for (int ch = 0; ch < 8; ch++) {
        int base = ch * 1024;
        __syncthreads();
#pragma unroll
        for (int i = 0; i < 4; i++) {
            int c = t + 256 * i;
            float4 p = cb[base + c];
            lx[c] = p.x; ly[c] = p.y; lz[c] = p.z; lw[c] = p.w;
        }
        __syncthreads();
#pragma unroll 2
        for (int s = 0; s < 16; s++) {
            int ci = s * 64 + lane;
            float jx = lx[ci], jy = ly[ci], jz = lz[ci], jw = lw[ci];
            float dot = fmaf(me.z, jz, fmaf(me.y, jy, me.x * jx));
            float d = fmaf(-2.f, dot, me.w) + jw;
            unsigned long long m = __ballot(d < tau);
            while (m) {
                int hl = __builtin_ctzll(m); m &= m - 1;
                float dn = __int_as_float(
                    __builtin_amdgcn_readlane(__float_as_int(d), hl));
                int jn = base + s * 64 + hl;      // scalar
                unsigned long long bl = __ballot(val < dn);
                int pos = __popcll(bl);           // insert position (lanes>=32 val=INF -> 0 bits)
                float sv = __shfl_up(val, 1, 64);
                int   sj = __shfl_up(vid, 1, 64);
                float nv = (lane > pos) ? sv : val; nv = (lane == pos) ? dn : nv;
                int   nj = (lane > pos) ? sj : vid; nj = (lane == pos) ? jn : nj;
                val = lt32 ? nv : val;
                vid = lt32 ? nj : vid;
                tau = __int_as_float(
                    __builtin_amdgcn_readlane(__float_as_int(val), 31));
            }
        }
    }
    if (lt32) pip[(size_t)pt * NCAND + lane] = vid;
}

// Exact refinement: recompute d for the 32 surviving candidates in fp64,
// select top-16 with lexicographic (d, index) tie-break.
// fp64 products of fp32 values are exact -> selection matches any fp64 golden ref.
__global__ __launch_bounds__(256) void k_refine(
    const float4* __restrict__ xyzw, const int* __restrict__ pip, int* __restrict__ idx)
{
    int pt = blockIdx.x * 256 + threadIdx.x;
    int b = pt >> 13;
    const float4* cb = xyzw + ((size_t)b << 13);
    float4 mef = cb[pt & 8191];
    double mx = (double)mef.x, my = (double)mef.y, mz = (double)mef.z;
    double msq = (mx * mx + my * my) + mz * mz;
    double bd[16]; int bi[16];
#pragma unroll
    for (int s = 0; s < 16; s++) { bd[s] = 1e300; bi[s] = 0x7fffffff; }
    for (int c = 0; c < NCAND; c++) {
        int j = pip[(size_t)pt * NCAND + c];
        float4 cj = cb[j];
        double jx = (double)cj.x, jy = (double)cj.y, jz = (double)cj.z;
        double dot = (mx * jx + my * jy) + mz * jz;
        double sqj = (jx * jx + jy * jy) + jz * jz;
        double d = (-2.0 * dot + msq) + sqj;
        if (d < bd[15] || (d == bd[15] && j < bi[15])) {
            double pd_ = d; int pi_ = j;
#pragma unroll
            for (int s = 15; s >= 1; s--) {
                bool cc = (pd_ < bd[s - 1]) || (pd_ == bd[s - 1] && pi_ < bi[s - 1]);
                double nd = cc ? bd[s - 1] : pd_;  int ni = cc ? bi[s - 1] : pi_;
                double npd = cc ? pd_ : bd[s - 1]; int npi = cc ? pi_ : bi[s - 1];
                bd[s] = nd; bi[s] = ni; pd_ = npd; pi_ = npi;
            }
            bd[0] = pd_; bi[0] = pi_;
        }
    }
#pragma unroll
    for (int s = 0; s < 16; s++) idx[(size_t)pt * 16 + s] = bi[s];
}

// Pass over all (pt,k): pre-BN h and v, accumulate per-channel sum/sumsq.
__global__ __launch_bounds__(256) void k_hv(
    const float4* __restrict__ xyzw, const int* __restrict__ idx,
    const float* __restrict__ F1, const float* __restrict__ F2, const float* __restrict__ FV,
    const float* __restrict__ relw, float* __restrict__ stats)
{
    int t = threadIdx.x;
    int lane = t & 63;
    int w = blockIdx.x * 4 + (t >> 6);   // 0..4095
    float rw0 = relw[0 * 64 + lane], rw1 = relw[1 * 64 + lane], rw2 = relw[2 * 64 + lane];
    float rw3 = relw[3 * 64 + lane], rw4 = relw[4 * 64 + lane], rw5 = relw[5 * 64 + lane];
    float sh = 0.f, sh2 = 0.f, sv = 0.f, sv2 = 0.f;
    for (int i = 0; i < 8; i++) {
        int ptu = __builtin_amdgcn_readfirstlane(w + i * 4096);
        int b = ptu >> 13;
        float4 me = xyzw[ptu];
        float F1v = F1[(size_t)ptu * 64 + lane];
        const int* ip = idx + (size_t)ptu * 16;
#pragma unroll
        for (int k = 0; k < 16; k++) {
            int g = (b << 13) + ip[k];
            float4 cj = xyzw[g];
            float rx = cj.x - me.x, ry = cj.y - me.y, rz = cj.z - me.z;
            float h = F1v + F2[(size_t)g * 64 + lane];
            h = fmaf(rw0, rx, h); h = fmaf(rw1, ry, h); h = fmaf(rw2, rz, h);
            float v = FV[(size_t)g * 64 + lane];
            v = fmaf(rw3, rx, v); v = fmaf(rw4, ry, v); v = fmaf(rw5, rz, v);
            sh += h; sh2 = fmaf(h, h, sh2);
            sv += v; sv2 = fmaf(v, v, sv2);
        }
    }
    atomicAdd(&stats[lane], sh);       atomicAdd(&stats[64 + lane], sh2);
    atomicAdd(&stats[128 + lane], sv); atomicAdd(&stats[192 + lane], sv2);
}

// Attention: BN(h)+relu -> logits -> softmax -> BN(v)+relu weighted sum -> Wo matvec -> o_pre + o stats
__global__ __launch_bounds__(256) void k_attn(
    const float4* __restrict__ xyzw, const int* __restrict__ idx,
    const float* __restrict__ F1, const float* __restrict__ F2, const float* __restrict__ FV,
    const float* __restrict__ relw, float* __restrict__ stats,
    const float* __restrict__ g1, const float* __restrict__ be1,
    const float* __restrict__ W2, const float* __restrict__ b2,
    const float* __restrict__ gv, const float* __restrict__ bev,
    const float* __restrict__ pwoT, const float* __restrict__ bo,
    float* __restrict__ opre)
{
    int t = threadIdx.x;
    int lane = t & 63;
    int wl = t >> 6;
    int w = blockIdx.x * 4 + wl;   // 0..8191
    const float invM = 1.f / 524288.f;
    float hm = stats[lane] * invM, hq = stats[64 + lane] * invM;
    float s1 = g1[lane] * rsqrtf(hq - hm * hm + EPSBN);
    float t1 = be1[lane] - s1 * hm;
    float vm = stats[128 + lane] * invM, vq = stats[192 + lane] * invM;
    float sv = gv[lane] * rsqrtf(vq - vm * vm + EPSBN);
    float tv = bev[lane] - sv * vm;
    float rw0 = relw[0 * 64 + lane], rw1 = relw[1 * 64 + lane], rw2 = relw[2 * 64 + lane];
    float rw3 = relw[3 * 64 + lane], rw4 = relw[4 * 64 + lane], rw5 = relw[5 * 64 + lane];
    float w2v = W2[lane];
    float b2v = b2[0];
    float bov = bo[lane];
    float so_ = 0.f, so2 = 0.f;
    __shared__ float lds_out[4][64];

    for (int i = 0; i < 4; i++) {
        int ptu = __builtin_amdgcn_readfirstlane(w + i * 8192);
        int b = ptu >> 13;
        float4 me = xyzw[ptu];
        float F1v = F1[(size_t)ptu * 64 + lane];
        const int* ip = idx + (size_t)ptu * 16;
        float ek[16], vk[16];
#pragma unroll
        for (int k = 0; k < 16; k++) {
            int g = (b << 13) + ip[k];
            float4 cj = xyzw[g];
            float rx = cj.x - me.x, ry = cj.y - me.y, rz = cj.z - me.z;
            float h = F1v + F2[(size_t)g * 64 + lane];
            h = fmaf(rw0, rx, h); h = fmaf(rw1, ry, h); h = fmaf(rw2, rz, h);
            float a = fmaxf(fmaf(s1, h, t1), 0.f);
            float v = FV[(size_t)g * 64 + lane];
            v = fmaf(rw3, rx, v); v = fmaf(rw4, ry, v); v = fmaf(rw5, rz, v);
            vk[k] = fmaxf(fmaf(sv, v, tv), 0.f);
            float lg = w2v * a;
#pragma unroll
            for (int off = 32; off >= 1; off >>= 1) lg += __shfl_xor(lg, off, 64);
            ek[k] = lg + b2v;
        }
        float mx = ek[0];
#pragma unroll
        for (int k = 1; k < 16; k++) mx = fmaxf(mx, ek[k]);
        float ssum = 0.f;
#pragma unroll
        for (int k = 0; k < 16; k++) { float e = __expf(ek[k] - mx); ek[k] = e; ssum += e; }
        float acc = 0.f;
#pragma unroll
        for (int k = 0; k < 16; k++) acc = fmaf(ek[k], vk[k], acc);
        float outv = acc / ssum;

        lds_out[wl][lane] = outv;
        __syncthreads();
        float op = bov;
        for (int c = 0; c < 64; c++)
            op = fmaf(pwoT[c * 64 + lane], lds_out[wl][c], op);
        opre[(size_t)ptu * 64 + lane] = op;
        so_ += op; so2 = fmaf(op, op, so2);
        __syncthreads();
    }
    atomicAdd(&stats[256 + lane], so_);
    atomicAdd(&stats[320 + lane], so2);
}

// Final: BN(o)+relu + residual feats, transpose [B,N,C]->[B,C,N]
__global__ __launch_bounds__(256) void k_final(
    const float* __restrict__ opre, const float* __restrict__ stats,
    const float* __restrict__ go, const float* __restrict__ beo,
    const float* __restrict__ feats, float* __restrict__ out)
{
    __shared__ float tile[64][65];
    int t = threadIdx.x;
    int blk = blockIdx.x;
    int b = blk >> 7, n0 = (blk & 127) << 6;
#pragma unroll
    for (int i = 0; i < 16; i++) {
        int e = t + i * 256;
        int r = e >> 6, c = e & 63;
        tile[r][c] = opre[((size_t)((b << 13) + n0 + r)) * 64 + c];
    }
    __syncthreads();
    const float invM = 1.f / 32768.f;
    int lane = t & 63, wv = t >> 6;
#pragma unroll
    for (int i = 0; i < 16; i++) {
        int c = wv * 16 + i;
        float om = stats[256 + c] * invM, oq = stats[320 + c] * invM;
        float so = go[c] * rsqrtf(oq - om * om + EPSBN);
        float to = beo[c] - so * om;
        float val = fmaxf(fmaf(so, tile[lane][c], to), 0.f);
        size_t oix = ((size_t)b * 64 + c) * NN + n0 + lane;
        out[oix] = val + feats[oix];
    }
}

extern "C" void kernel_launch(void* const* d_in, const int* in_sizes, int n_in,
                              void* d_out, int out_size, void* d_ws, size_t ws_size,
                              hipStream_t stream)
{
    const float* xyz  = (const float*)d_in[0];
    const float* feats= (const float*)d_in[1];
    const float* W1   = (const float*)d_in[2];
    const float* b1   = (const float*)d_in[3];
    const float* g1   = (const float*)d_in[4];
    const float* be1  = (const float*)d_in[5];
    const float* W2   = (const float*)d_in[6];
    const float* b2   = (const float*)d_in[7];
    const float* Wv   = (const float*)d_in[8];
    const float* bv   = (const float*)d_in[9];
    const float* gv   = (const float*)d_in[10];
    const float* bev  = (const float*)d_in[11];
    const float* Wo   = (const float*)d_in[12];
    const float* bo   = (const float*)d_in[13];
    const float* go   = (const float*)d_in[14];
    const float* beo  = (const float*)d_in[15];

    float* ws = (float*)d_ws;
    float* xyzw  = ws + OFF_XYZW;
    float* pw1aT = ws + OFF_PW1AT;
    float* pw1bT = ws + OFF_PW1BT;
    float* pwvaT = ws + OFF_PWVAT;
    float* pwoT  = ws + OFF_PWOT;
    float* relw  = ws + OFF_RELW;
    float* stats = ws + OFF_STATS;
    int*   idx   = (int*)(ws + OFF_IDX);
    int*   pip   = (int*)(ws + OFF_PIP);
    float* F1    = ws + OFF_F1;
    float* F2    = ws + OFF_F2;
    float* FV    = ws + OFF_FV;
    float* opre  = ws + OFF_OPRE;   // aliases pip (dead after k_refine)

    k_prep<<<129, 256, 0, stream>>>(xyz, W1, Wv, Wo, xyzw, pw1aT, pw1bT, pwvaT, pwoT, relw, stats);
    k_F<<<512, 256, 0, stream>>>(feats, b1, bv, pw1aT, pw1bT, pwvaT, F1, F2, FV);
    k_knn<<<8192, 256, 0, stream>>>((const float4*)xyzw, pip);
    k_refine<<<128, 256, 0, stream>>>((const float4*)xyzw, pip, idx);
    k_hv<<<1024, 256, 0, stream>>>((const float4*)xyzw, idx, F1, F2, FV, relw, stats);
    k_attn<<<2048, 256, 0, stream>>>((const float4*)xyzw, idx, F1, F2, FV, relw, stats,
                                     g1, be1, W2, b2, gv, bev, pwoT, bo, opre);
    k_final<<<512, 256, 0, stream>>>(opre, stats, go, beo, feats, (float*)d_out);
}

// Round 6
// 660.837 us; speedup vs baseline: 1.7822x; 1.1595x over previous
//
#include <hip/hip_runtime.h>
#include <math.h>

// Problem constants
#define BB 4
#define NN 8192
#define CC 64
#define KK 16
#define HH 64
#define NPTS (BB*NN)   // 32768
#define EPSBN 1e-5f
#define NCAND 32       // fp32 prefilter keeps top-32 per query; fp64 refine picks 16
#define NCELL 4096     // 16^3 Morton cells
#define NCHUNK 32      // 256-point chunks per batch
#define CHSZ 256

// ---------------- ws layout (float offsets) ----------------
#define OFF_XYZW  0
#define OFF_PW1AT 131072
#define OFF_PW1BT 135168
#define OFF_PWVAT 139264
#define OFF_PWOT  143360
#define OFF_RELW  147456
#define OFF_STATS 147840
#define OFF_IDX   148224
#define OFF_PIP   672512      // pip: 32768*32 ints = 1048576 slots
#define OFF_OPRE  672512      // OPRE aliases PIP (dead after k_refine)
// sort scratch lives in [2769664, 4866816) — free gap after OPRE end
#define OFF_SX4   2769664     // sorted xyzw [4][8192] float4 = 131072
#define OFF_SID   2900736     // sorted orig ids [4][8192] int = 32768
#define OFF_HIST  2933504     // [4][4096] int = 16384
#define OFF_BB    2949888     // bbmin[128] float4 + bbmax[128] float4 = 1024
#define OFF_F1    4866816
#define OFF_F2    6963968
#define OFF_FV    9061120

__device__ __forceinline__ int morton_cell(float x, float y, float z) {
    int cx = (int)floorf((x + 4.f) * 2.f);
    int cy = (int)floorf((y + 4.f) * 2.f);
    int cz = (int)floorf((z + 4.f) * 2.f);
    cx = cx < 0 ? 0 : (cx > 15 ? 15 : cx);
    cy = cy < 0 ? 0 : (cy > 15 ? 15 : cy);
    cz = cz < 0 ? 0 : (cz > 15 ? 15 : cz);
    int ex = (cx & 1) | ((cx & 2) << 2) | ((cx & 4) << 4) | ((cx & 8) << 6);
    int ey = (cy & 1) | ((cy & 2) << 2) | ((cy & 4) << 4) | ((cy & 8) << 6);
    int ez = (cz & 1) | ((cz & 2) << 2) | ((cz & 4) << 4) | ((cz & 8) << 6);
    return ex | (ey << 1) | (ez << 2);
}

__device__ __forceinline__ float distf(float4 me, float jx, float jy, float jz, float jw) {
    float dot = fmaf(me.z, jz, fmaf(me.y, jy, me.x * jx));
    return fmaf(-2.f, dot, me.w) + jw;
}

__device__ __forceinline__ float mind2(float4 me, float4 bmin, float4 bmax) {
    float dx = fmaxf(fmaxf(bmin.x - me.x, me.x - bmax.x), 0.f);
    float dy = fmaxf(fmaxf(bmin.y - me.y, me.y - bmax.y), 0.f);
    float dz = fmaxf(fmaxf(bmin.z - me.z, me.z - bmax.z), 0.f);
    return fmaf(dx, dx, fmaf(dy, dy, dz * dz));
}

__global__ __launch_bounds__(256) void k_zero(int* __restrict__ hist) {
    int t = threadIdx.x;
    for (int i = t; i < BB * NCELL; i += 256) hist[i] = 0;
}

__global__ __launch_bounds__(256) void k_prep(
    const float* __restrict__ xyz, const float* __restrict__ W1,
    const float* __restrict__ Wv, const float* __restrict__ Wo,
    float* __restrict__ xyzw, int* __restrict__ hist,
    float* __restrict__ pw1aT, float* __restrict__ pw1bT,
    float* __restrict__ pwvaT, float* __restrict__ pwoT, float* __restrict__ relw,
    float* __restrict__ stats)
{
    int t = threadIdx.x;
    int bid = blockIdx.x;
    if (bid < 128) {
        int pt = bid * 256 + t;
        int b = pt >> 13, n = pt & 8191;
        const float* xb = xyz + (size_t)b * 3 * NN;
        float x = xb[n], y = xb[NN + n], z = xb[2 * NN + n];
        float sq = __fadd_rn(__fadd_rn(__fmul_rn(x, x), __fmul_rn(y, y)), __fmul_rn(z, z));
        ((float4*)xyzw)[pt] = make_float4(x, y, z, sq);
        atomicAdd(&hist[b * NCELL + morton_cell(x, y, z)], 1);
    } else {
        for (int e = t; e < 4096; e += 256) {
            int c = e >> 6, o = e & 63;
            pw1aT[e] = W1[o * 131 + c];
            pw1bT[e] = W1[o * 131 + 64 + c];
            pwvaT[e] = Wv[o * 67 + c];
            pwoT[e]  = Wo[o * 64 + c];
        }
        for (int e = t; e < 384; e += 256) {
            int d = e >> 6, o = e & 63;
            relw[e] = (d < 3) ? W1[o * 131 + 128 + d] : Wv[o * 67 + 64 + (d - 3)];
            stats[e] = 0.0f;
        }
    }
}

// Exclusive scan of per-batch 4096-bin histogram (in place), one block per batch.
__global__ __launch_bounds__(256) void k_scan(int* __restrict__ hist) {
    __shared__ int part[256];
    int b = blockIdx.x, t = threadIdx.x;
    int* h = hist + b * NCELL;
    int loc[16]; int s = 0;
#pragma unroll
    for (int i = 0; i < 16; i++) { loc[i] = h[t * 16 + i]; s += loc[i]; }
    part[t] = s;
    __syncthreads();
    for (int off = 1; off < 256; off <<= 1) {
        int v = (t >= off) ? part[t - off] : 0;
        __syncthreads();
        part[t] += v;
        __syncthreads();
    }
    int run = (t > 0) ? part[t - 1] : 0;
#pragma unroll
    for (int i = 0; i < 16; i++) { int c = loc[i]; h[t * 16 + i] = run; run += c; }
}

__global__ __launch_bounds__(256) void k_scatter(
    const float4* __restrict__ xyzw, int* __restrict__ off,
    float4* __restrict__ sx4, int* __restrict__ sid)
{
    int pt = blockIdx.x * 256 + threadIdx.x;
    int b = pt >> 13, n = pt & 8191;
    float4 p = xyzw[pt];
    int cell = morton_cell(p.x, p.y, p.z);
    int dst = atomicAdd(&off[b * NCELL + cell], 1);
    sx4[(b << 13) + dst] = p;
    sid[(b << 13) + dst] = n;
}

// Per-chunk bbox over 256 sorted points. block = chunk (0..127 global).
__global__ __launch_bounds__(256) void k_bbox(
    const float4* __restrict__ sx4, float4* __restrict__ bbmin, float4* __restrict__ bbmax)
{
    __shared__ float smn[4][3], smx[4][3];
    int ch = blockIdx.x, t = threadIdx.x, lane = t & 63, wl = t >> 6;
    float4 p = sx4[ch * 256 + t];
    float mnx = p.x, mny = p.y, mnz = p.z, mxx = p.x, mxy = p.y, mxz = p.z;
#pragma unroll
    for (int o = 32; o >= 1; o >>= 1) {
        mnx = fminf(mnx, __shfl_xor(mnx, o, 64)); mxx = fmaxf(mxx, __shfl_xor(mxx, o, 64));
        mny = fminf(mny, __shfl_xor(mny, o, 64)); mxy = fmaxf(mxy, __shfl_xor(mxy, o, 64));
        mnz = fminf(mnz, __shfl_xor(mnz, o, 64)); mxz = fmaxf(mxz, __shfl_xor(mxz, o, 64));
    }
    if (lane == 0) { smn[wl][0]=mnx; smn[wl][1]=mny; smn[wl][2]=mnz;
                     smx[wl][0]=mxx; smx[wl][1]=mxy; smx[wl][2]=mxz; }
    __syncthreads();
    if (t == 0) {
        float a0=smn[0][0], a1=smn[0][1], a2=smn[0][2];
        float b0=smx[0][0], b1=smx[0][1], b2=smx[0][2];
        for (int w = 1; w < 4; w++) {
            a0=fminf(a0,smn[w][0]); a1=fminf(a1,smn[w][1]); a2=fminf(a2,smn[w][2]);
            b0=fmaxf(b0,smx[w][0]); b1=fmaxf(b1,smx[w][1]); b2=fmaxf(b2,smx[w][2]);
        }
        bbmin[ch] = make_float4(a0,a1,a2,0.f);
        bbmax[ch] = make_float4(b0,b1,b2,0.f);
    }
}

// Wave-cooperative KNN with warm-start window sort + bbox chunk pruning.
// One query (sorted order) per wave; sorted top-32 in lanes 0..31, tau = 32nd.
__global__ __launch_bounds__(256) void k_knn(
    const float4* __restrict__ sx4, const int* __restrict__ sid,
    const float4* __restrict__ bbmin, const float4* __restrict__ bbmax,
    int* __restrict__ pip)
{
    __shared__ float lx[256], ly[256], lz[256], lw[256];
    __shared__ int lid[256];
    __shared__ unsigned int wmask[4];
    int t = threadIdx.x, lane = t & 63, wl = t >> 6;
    int gq = blockIdx.x * 4 + wl;
    int b = __builtin_amdgcn_readfirstlane(gq >> 13);
    int qs = gq & 8191;
    const float4* sb = sx4 + ((size_t)b << 13);
    const int* ib = sid + ((size_t)b << 13);
    float4 me = sb[qs];                       // wave-uniform
    int myorig = ib[qs];
    const float INF = 3.402823466e38f;

    // phase 1: sort the 64-point positional window (spatially local -> warm tau)
    int ws0 = qs - 32; ws0 = ws0 < 0 ? 0 : (ws0 > (NN - 64) ? (NN - 64) : ws0);
    float4 cp = sb[ws0 + lane];
    int cid = ib[ws0 + lane];
    float d = distf(me, cp.x, cp.y, cp.z, cp.w);
#pragma unroll
    for (int k2 = 2; k2 <= 64; k2 <<= 1) {
#pragma unroll
        for (int j2 = k2 >> 1; j2 >= 1; j2 >>= 1) {
            float od = __shfl_xor(d, j2, 64);
            int   oi = __shfl_xor(cid, j2, 64);
            bool up = ((lane & k2) == 0);
            bool lower = ((lane & j2) == 0);
            bool wantMin = (lower == up);
            bool to = wantMin ? (od < d) : (od > d);
            d = to ? od : d; cid = to ? oi : cid;
        }
    }
    bool lt32 = (lane < 32);
    float val = lt32 ? d : INF;
    int vid = cid;
    float tau = __int_as_float(__builtin_amdgcn_readlane(__float_as_int(val), 31));

    // phase 2a: chunk mask vs warm tau (exact bound + safety margin)
    unsigned int m32 = 0;
    for (int c = 0; c < NCHUNK; c++) {
        float md = mind2(me, bbmin[b * NCHUNK + c], bbmax[b * NCHUNK + c]);
        if (md <= tau * 1.0001f + 1e-5f) m32 |= (1u << c);
    }
    if (lane == 0) wmask[wl] = m32;
    __syncthreads();
    unsigned int bm = wmask[0] | wmask[1] | wmask[2] | wmask[3];  // block-uniform

    // phase 2b: scan surviving chunks (window positions excluded -> no dups)
    while (bm) {
        int c = __builtin_ctz(bm); bm &= bm - 1;
        __syncthreads();
        {
            float4 p = sb[c * 256 + t];
            lx[t] = p.x; ly[t] = p.y; lz[t] = p.z; lw[t] = p.w;
            lid[t] = ib[c * 256 + t];
        }
        __syncthreads();
        float md = mind2(me, bbmin[b * NCHUNK + c], bbmax[b * NCHUNK + c]);
        if (md <= tau * 1.0001f + 1e-5f) {
#pragma unroll 2
            for (int s = 0; s < 4; s++) {
                int ci = s * 64 + lane;
                int pos = c * 256 + ci;
                float dd = distf(me, lx[ci], ly[ci], lz[ci], lw[ci]);
                bool inwin = (pos >= ws0) && (pos < ws0 + 64);
                dd = inwin ? INF : dd;
                int myid = lid[ci];
                unsigned long long m = __ballot(dd < tau);
                while (m) {
                    int hl = __builtin_ctzll(m); m &= m - 1;
                    float dn = __int_as_float(
                        __builtin_amdgcn_readlane(__float_as_int(dd), hl));
                    int jn = __builtin_amdgcn_readlane(myid, hl);
                    unsigned long long bl = __ballot(val < dn);
                    int pos2 = __popcll(bl);
                    float sv = __shfl_up(val, 1, 64);
                    int   sj = __shfl_up(vid, 1, 64);
                    float nv = (lane > pos2) ? sv : val; nv = (lane == pos2) ? dn : nv;
                    int   nj = (lane > pos2) ? sj : vid; nj = (lane == pos2) ? jn : nj;
                    val = lt32 ? nv : val;
                    vid = lt32 ? nj : vid;
                    tau = __int_as_float(__builtin_amdgcn_readlane(__float_as_int(val), 31));
                }
            }
        }
    }
    if (lt32) pip[(size_t)(((b << 13) + myorig)) * NCAND + lane] = vid;
}

// Exact refinement: recompute d for the 32 surviving candidates in fp64,
// select top-16 with lexicographic (d, index) tie-break.
__global__ __launch_bounds__(256) void k_refine(
    const float4* __restrict__ xyzw, const int* __restrict__ pip, int* __restrict__ idx)
{
    int pt = blockIdx.x * 256 + threadIdx.x;
    int b = pt >> 13;
    const float4* cb = xyzw + ((size_t)b << 13);
    float4 mef = cb[pt & 8191];
    double mx = (double)mef.x, my = (double)mef.y, mz = (double)mef.z;
    double msq = (mx * mx + my * my) + mz * mz;
    double bd[16]; int bi[16];
#pragma unroll
    for (int s = 0; s < 16; s++) { bd[s] = 1e300; bi[s] = 0x7fffffff; }
    for (int c = 0; c < NCAND; c++) {
        int j = pip[(size_t)pt * NCAND + c];
        float4 cj = cb[j];
        double jx = (double)cj.x, jy = (double)cj.y, jz = (double)cj.z;
        double dot = (mx * jx + my * jy) + mz * jz;
        double sqj = (jx * jx + jy * jy) + jz * jz;
        double dd = (-2.0 * dot + msq) + sqj;
        if (dd < bd[15] || (dd == bd[15] && j < bi[15])) {
            double pd_ = dd; int pi_ = j;
#pragma unroll
            for (int s = 15; s >= 1; s--) {
                bool cc = (pd_ < bd[s - 1]) || (pd_ == bd[s - 1] && pi_ < bi[s - 1]);
                double nd = cc ? bd[s - 1] : pd_;  int ni = cc ? bi[s - 1] : pi_;
                double npd = cc ? pd_ : bd[s - 1]; int npi = cc ? pi_ : bi[s - 1];
                bd[s] = nd; bi[s] = ni; pd_ = npd; pi_ = npi;
            }
            bd[0] = pd_; bi[0] = pi_;
        }
    }
#pragma unroll
    for (int s = 0; s < 16; s++) idx[(size_t)pt * 16 + s] = bi[s];
}

// Per-point GEMVs: F1 = b1 + W1a*feat, F2 = W1b*feat, FV = bv + Wva*feat
__global__ __launch_bounds__(256) void k_F(
    const float* __restrict__ feats, const float* __restrict__ b1, const float* __restrict__ bv,
    const float* __restrict__ pw1aT, const float* __restrict__ pw1bT, const float* __restrict__ pwvaT,
    float* __restrict__ F1, float* __restrict__ F2, float* __restrict__ FV)
{
    int t = threadIdx.x;
    int lane = t & 63;
    int wave = t >> 6;
    int pt0 = blockIdx.x * 64 + wave * 16;
    int b   = __builtin_amdgcn_readfirstlane(pt0 >> 13);
    int n0  = __builtin_amdgcn_readfirstlane(pt0 & 8191);
    const float* fb = feats + (size_t)b * CC * NN;
    float accA[16], accB[16], accV[16];
    float bb1 = b1[lane], bbv = bv[lane];
#pragma unroll
    for (int p = 0; p < 16; p++) { accA[p] = bb1; accB[p] = 0.f; accV[p] = bbv; }
    for (int c = 0; c < 64; c++) {
        float wA = pw1aT[c * 64 + lane];
        float wB = pw1bT[c * 64 + lane];
        float wV = pwvaT[c * 64 + lane];
        const float* fr = fb + (size_t)c * NN + n0;
#pragma unroll
        for (int p = 0; p < 16; p++) {
            float f = fr[p];
            accA[p] = fmaf(wA, f, accA[p]);
            accB[p] = fmaf(wB, f, accB[p]);
            accV[p] = fmaf(wV, f, accV[p]);
        }
    }
#pragma unroll
    for (int p = 0; p < 16; p++) {
        int pt = pt0 + p;
        F1[(size_t)pt * 64 + lane] = accA[p];
        F2[(size_t)pt * 64 + lane] = accB[p];
        FV[(size_t)pt * 64 + lane] = accV[p];
    }
}

// Pass over all (pt,k): pre-BN h and v, accumulate per-channel sum/sumsq.
__global__ __launch_bounds__(256) void k_hv(
    const float4* __restrict__ xyzw, const int* __restrict__ idx,
    const float* __restrict__ F1, const float* __restrict__ F2, const float* __restrict__ FV,
    const float* __restrict__ relw, float* __restrict__ stats)
{
    int t = threadIdx.x;
    int lane = t & 63;
    int w = blockIdx.x * 4 + (t >> 6);
    float rw0 = relw[0 * 64 + lane], rw1 = relw[1 * 64 + lane], rw2 = relw[2 * 64 + lane];
    float rw3 = relw[3 * 64 + lane], rw4 = relw[4 * 64 + lane], rw5 = relw[5 * 64 + lane];
    float sh = 0.f, sh2 = 0.f, sv = 0.f, sv2 = 0.f;
    for (int i = 0; i < 8; i++) {
        int ptu = __builtin_amdgcn_readfirstlane(w + i * 4096);
        int b = ptu >> 13;
        float4 me = xyzw[ptu];
        float F1v = F1[(size_t)ptu * 64 + lane];
        const int* ip = idx + (size_t)ptu * 16;
#pragma unroll
        for (int k = 0; k < 16; k++) {
            int g = (b << 13) + ip[k];
            float4 cj = xyzw[g];
            float rx = cj.x - me.x, ry = cj.y - me.y, rz = cj.z - me.z;
            float h = F1v + F2[(size_t)g * 64 + lane];
            h = fmaf(rw0, rx, h); h = fmaf(rw1, ry, h); h = fmaf(rw2, rz, h);
            float v = FV[(size_t)g * 64 + lane];
            v = fmaf(rw3, rx, v); v = fmaf(rw4, ry, v); v = fmaf(rw5, rz, v);
            sh += h; sh2 = fmaf(h, h, sh2);
            sv += v; sv2 = fmaf(v, v, sv2);
        }
    }
    atomicAdd(&stats[lane], sh);       atomicAdd(&stats[64 + lane], sh2);
    atomicAdd(&stats[128 + lane], sv); atomicAdd(&stats[192 + lane], sv2);
}

// Attention: BN(h)+relu -> logits -> softmax -> BN(v)+relu weighted sum -> Wo matvec
__global__ __launch_bounds__(256) void k_attn(
    const float4* __restrict__ xyzw, const int* __restrict__ idx,
    const float* __restrict__ F1, const float* __restrict__ F2, const float* __restrict__ FV,
    const float* __restrict__ relw, float* __restrict__ stats,
    const float* __restrict__ g1, const float* __restrict__ be1,
    const float* __restrict__ W2, const float* __restrict__ b2,
    const float* __restrict__ gv, const float* __restrict__ bev,
    const float* __restrict__ pwoT, const float* __restrict__ bo,
    float* __restrict__ opre)
{
    int t = threadIdx.x;
    int lane = t & 63;
    int wl = t >> 6;
    int w = blockIdx.x * 4 + wl;
    const float invM = 1.f / 524288.f;
    float hm = stats[lane] * invM, hq = stats[64 + lane] * invM;
    float s1 = g1[lane] * rsqrtf(hq - hm * hm + EPSBN);
    float t1 = be1[lane] - s1 * hm;
    float vm = stats[128 + lane] * invM, vq = stats[192 + lane] * invM;
    float sv = gv[lane] * rsqrtf(vq - vm * vm + EPSBN);
    float tv = bev[lane] - sv * vm;
    float rw0 = relw[0 * 64 + lane], rw1 = relw[1 * 64 + lane], rw2 = relw[2 * 64 + lane];
    float rw3 = relw[3 * 64 + lane], rw4 = relw[4 * 64 + lane], rw5 = relw[5 * 64 + lane];
    float w2v = W2[lane];
    float b2v = b2[0];
    float bov = bo[lane];
    float so_ = 0.f, so2 = 0.f;
    __shared__ float lds_out[4][64];

    for (int i = 0; i < 4; i++) {
        int ptu = __builtin_amdgcn_readfirstlane(w + i * 8192);
        int b = ptu >> 13;
        float4 me = xyzw[ptu];
        float F1v = F1[(size_t)ptu * 64 + lane];
        const int* ip = idx + (size_t)ptu * 16;
        float ek[16], vk[16];
#pragma unroll
        for (int k = 0; k < 16; k++) {
            int g = (b << 13) + ip[k];
            float4 cj = xyzw[g];
            float rx = cj.x - me.x, ry = cj.y - me.y, rz = cj.z - me.z;
            float h = F1v + F2[(size_t)g * 64 + lane];
            h = fmaf(rw0, rx, h); h = fmaf(rw1, ry, h); h = fmaf(rw2, rz, h);
            float a = fmaxf(fmaf(s1, h, t1), 0.f);
            float v = FV[(size_t)g * 64 + lane];
            v = fmaf(rw3, rx, v); v = fmaf(rw4, ry, v); v = fmaf(rw5, rz, v);
            vk[k] = fmaxf(fmaf(sv, v, tv), 0.f);
            float lg = w2v * a;
#pragma unroll
            for (int off = 32; off >= 1; off >>= 1) lg += __shfl_xor(lg, off, 64);
            ek[k] = lg + b2v;
        }
        float mx = ek[0];
#pragma unroll
        for (int k = 1; k < 16; k++) mx = fmaxf(mx, ek[k]);
        float ssum = 0.f;
#pragma unroll
        for (int k = 0; k < 16; k++) { float e = __expf(ek[k] - mx); ek[k] = e; ssum += e; }
        float acc = 0.f;
#pragma unroll
        for (int k = 0; k < 16; k++) acc = fmaf(ek[k], vk[k], acc);
        float outv = acc / ssum;

        lds_out[wl][lane] = outv;
        __syncthreads();
        float op = bov;
        for (int c = 0; c < 64; c++)
            op = fmaf(pwoT[c * 64 + lane], lds_out[wl][c], op);
        opre[(size_t)ptu * 64 + lane] = op;
        so_ += op; so2 = fmaf(op, op, so2);
        __syncthreads();
    }
    atomicAdd(&stats[256 + lane], so_);
    atomicAdd(&stats[320 + lane], so2);
}

// Final: BN(o)+relu + residual feats, transpose [B,N,C]->[B,C,N]
__global__ __launch_bounds__(256) void k_final(
    const float* __restrict__ opre, const float* __restrict__ stats,
    const float* __restrict__ go, const float* __restrict__ beo,
    const float* __restrict__ feats, float* __restrict__ out)
{
    __shared__ float tile[64][65];
    int t = threadIdx.x;
    int blk = blockIdx.x;
    int b = blk >> 7, n0 = (blk & 127) << 6;
#pragma unroll
    for (int i = 0; i < 16; i++) {
        int e = t + i * 256;
        int r = e >> 6, c = e & 63;
        tile[r][c] = opre[((size_t)((b << 13) + n0 + r)) * 64 + c];
    }
    __syncthreads();
    const float invM = 1.f / 32768.f;
    int lane = t & 63, wv = t >> 6;
#pragma unroll
    for (int i = 0; i < 16; i++) {
        int c = wv * 16 + i;
        float om = stats[256 + c] * invM, oq = stats[320 + c] * invM;
        float so = go[c] * rsqrtf(oq - om * om + EPSBN);
        float to = beo[c] - so * om;
        float val = fmaxf(fmaf(so, tile[lane][c], to), 0.f);
        size_t oix = ((size_t)b * 64 + c) * NN + n0 + lane;
        out[oix] = val + feats[oix];
    }
}

extern "C" void kernel_launch(void* const* d_in, const int* in_sizes, int n_in,
                              void* d_out, int out_size, void* d_ws, size_t ws_size,
                              hipStream_t stream)
{
    const float* xyz  = (const float*)d_in[0];
    const float* feats= (const float*)d_in[1];
    const float* W1   = (const float*)d_in[2];
    const float* b1   = (const float*)d_in[3];
    const float* g1   = (const float*)d_in[4];
    const float* be1  = (const float*)d_in[5];
    const float* W2   = (const float*)d_in[6];
    const float* b2   = (const float*)d_in[7];
    const float* Wv   = (const float*)d_in[8];
    const float* bv   = (const float*)d_in[9];
    const float* gv   = (const float*)d_in[10];
    const float* bev  = (const float*)d_in[11];
    const float* Wo   = (const float*)d_in[12];
    const float* bo   = (const float*)d_in[13];
    const float* go   = (const float*)d_in[14];
    const float* beo  = (const float*)d_in[15];

    float* ws = (float*)d_ws;
    float* xyzw  = ws + OFF_XYZW;
    float* pw1aT = ws + OFF_PW1AT;
    float* pw1bT = ws + OFF_PW1BT;
    float* pwvaT = ws + OFF_PWVAT;
    float* pwoT  = ws + OFF_PWOT;
    float* relw  = ws + OFF_RELW;
    float* stats = ws + OFF_STATS;
    int*   idx   = (int*)(ws + OFF_IDX);
    int*   pip   = (int*)(ws + OFF_PIP);
    float4* sx4  = (float4*)(ws + OFF_SX4);
    int*   sid   = (int*)(ws + OFF_SID);
    int*   hist  = (int*)(ws + OFF_HIST);
    float4* bbmn = (float4*)(ws + OFF_BB);
    float4* bbmx = (float4*)(ws + OFF_BB + 512);
    float* F1    = ws + OFF_F1;
    float* F2    = ws + OFF_F2;
    float* FV    = ws + OFF_FV;
    float* opre  = ws + OFF_OPRE;   // aliases pip (dead after k_refine)

    k_zero<<<1, 256, 0, stream>>>(hist);
    k_prep<<<129, 256, 0, stream>>>(xyz, W1, Wv, Wo, xyzw, hist,
                                    pw1aT, pw1bT, pwvaT, pwoT, relw, stats);
    k_F<<<512, 256, 0, stream>>>(feats, b1, bv, pw1aT, pw1bT, pwvaT, F1, F2, FV);
    k_scan<<<4, 256, 0, stream>>>(hist);
    k_scatter<<<128, 256, 0, stream>>>((const float4*)xyzw, hist, sx4, sid);
    k_bbox<<<128, 256, 0, stream>>>((const float4*)sx4, bbmn, bbmx);
    k_knn<<<8192, 256, 0, stream>>>((const float4*)sx4, sid, bbmn, bbmx, pip);
    k_refine<<<128, 256, 0, stream>>>((const float4*)xyzw, pip, idx);
    k_hv<<<1024, 256, 0, stream>>>((const float4*)xyzw, idx, F1, F2, FV, relw, stats);
    k_attn<<<2048, 256, 0, stream>>>((const float4*)xyzw, idx, F1, F2, FV, relw, stats,
                                     g1, be1, W2, b2, gv, bev, pwoT, bo, opre);
    k_final<<<512, 256, 0, stream>>>(opre, stats, go, beo, feats, (float*)d_out);
}

// Round 7
// 581.789 us; speedup vs baseline: 2.0243x; 1.1359x over previous
//
#include <hip/hip_runtime.h>
#include <math.h>

// Problem constants
#define BB 4
#define NN 8192
#define CC 64
#define KK 16
#define HH 64
#define NPTS (BB*NN)   // 32768
#define EPSBN 1e-5f
#define NCAND 32       // fp32 prefilter keeps top-32; fp64 refine picks 16
#define NCELL 4096     // 16^3 Morton cells
#define NCHUNK 32      // 256-point chunks per batch

// ---------------- ws layout (float offsets) ----------------
#define OFF_XYZW  0
#define OFF_PW1AT 131072
#define OFF_PW1BT 135168
#define OFF_PWVAT 139264
#define OFF_PWOT  143360
#define OFF_RELW  147456
#define OFF_STATS 147840
#define OFF_IDX   148224      // idx: 32768*16 ints (SORTED-space neighbor ids)
#define OFF_PIP   672512      // pip: 32768*32 ints (sorted-space candidates)
#define OFF_OPRE  672512      // OPRE aliases PIP (dead after k_refine); 2097152 floats -> ends 2769664
#define OFF_SX4   2769664     // sorted xyzw [4][8192] float4
#define OFF_SID   2900736     // sorted->orig ids [4][8192] int
#define OFF_HIST  2933504     // [4][4096] int
#define OFF_BB    2949888     // bbmin[128] f4 + bbmax[128] f4
#define OFF_RANK  2950912     // orig->sorted rank [4][8192] int
#define OFF_F1    4866816     // SORTED layout
#define OFF_F2    6963968     // SORTED layout
#define OFF_FV    9061120     // SORTED layout

__device__ __forceinline__ int morton_cell(float x, float y, float z) {
    int cx = (int)floorf((x + 4.f) * 2.f);
    int cy = (int)floorf((y + 4.f) * 2.f);
    int cz = (int)floorf((z + 4.f) * 2.f);
    cx = cx < 0 ? 0 : (cx > 15 ? 15 : cx);
    cy = cy < 0 ? 0 : (cy > 15 ? 15 : cy);
    cz = cz < 0 ? 0 : (cz > 15 ? 15 : cz);
    int ex = (cx & 1) | ((cx & 2) << 2) | ((cx & 4) << 4) | ((cx & 8) << 6);
    int ey = (cy & 1) | ((cy & 2) << 2) | ((cy & 4) << 4) | ((cy & 8) << 6);
    int ez = (cz & 1) | ((cz & 2) << 2) | ((cz & 4) << 4) | ((cz & 8) << 6);
    return ex | (ey << 1) | (ez << 2);
}

__device__ __forceinline__ float distf(float4 me, float jx, float jy, float jz, float jw) {
    float dot = fmaf(me.z, jz, fmaf(me.y, jy, me.x * jx));
    return fmaf(-2.f, dot, me.w) + jw;
}

__device__ __forceinline__ float mind2(float4 me, float4 bmin, float4 bmax) {
    float dx = fmaxf(fmaxf(bmin.x - me.x, me.x - bmax.x), 0.f);
    float dy = fmaxf(fmaxf(bmin.y - me.y, me.y - bmax.y), 0.f);
    float dz = fmaxf(fmaxf(bmin.z - me.z, me.z - bmax.z), 0.f);
    return fmaf(dx, dx, fmaf(dy, dy, dz * dz));
}

__global__ __launch_bounds__(256) void k_zero(int* __restrict__ hist) {
    int t = threadIdx.x;
    for (int i = t; i < BB * NCELL; i += 256) hist[i] = 0;
}

__global__ __launch_bounds__(256) void k_prep(
    const float* __restrict__ xyz, const float* __restrict__ W1,
    const float* __restrict__ Wv, const float* __restrict__ Wo,
    float* __restrict__ xyzw, int* __restrict__ hist,
    float* __restrict__ pw1aT, float* __restrict__ pw1bT,
    float* __restrict__ pwvaT, float* __restrict__ pwoT, float* __restrict__ relw,
    float* __restrict__ stats)
{
    int t = threadIdx.x;
    int bid = blockIdx.x;
    if (bid < 128) {
        int pt = bid * 256 + t;
        int b = pt >> 13, n = pt & 8191;
        const float* xb = xyz + (size_t)b * 3 * NN;
        float x = xb[n], y = xb[NN + n], z = xb[2 * NN + n];
        float sq = __fadd_rn(__fadd_rn(__fmul_rn(x, x), __fmul_rn(y, y)), __fmul_rn(z, z));
        ((float4*)xyzw)[pt] = make_float4(x, y, z, sq);
        atomicAdd(&hist[b * NCELL + morton_cell(x, y, z)], 1);
    } else {
        for (int e = t; e < 4096; e += 256) {
            int c = e >> 6, o = e & 63;
            pw1aT[e] = W1[o * 131 + c];
            pw1bT[e] = W1[o * 131 + 64 + c];
            pwvaT[e] = Wv[o * 67 + c];
            pwoT[e]  = Wo[o * 64 + c];
        }
        for (int e = t; e < 384; e += 256) {
            int d = e >> 6, o = e & 63;
            relw[e] = (d < 3) ? W1[o * 131 + 128 + d] : Wv[o * 67 + 64 + (d - 3)];
            stats[e] = 0.0f;
        }
    }
}

// Exclusive scan of per-batch 4096-bin histogram (in place), one block per batch.
__global__ __launch_bounds__(256) void k_scan(int* __restrict__ hist) {
    __shared__ int part[256];
    int b = blockIdx.x, t = threadIdx.x;
    int* h = hist + b * NCELL;
    int loc[16]; int s = 0;
#pragma unroll
    for (int i = 0; i < 16; i++) { loc[i] = h[t * 16 + i]; s += loc[i]; }
    part[t] = s;
    __syncthreads();
    for (int off = 1; off < 256; off <<= 1) {
        int v = (t >= off) ? part[t - off] : 0;
        __syncthreads();
        part[t] += v;
        __syncthreads();
    }
    int run = (t > 0) ? part[t - 1] : 0;
#pragma unroll
    for (int i = 0; i < 16; i++) { int c = loc[i]; h[t * 16 + i] = run; run += c; }
}

__global__ __launch_bounds__(256) void k_scatter(
    const float4* __restrict__ xyzw, int* __restrict__ off,
    float4* __restrict__ sx4, int* __restrict__ sid, int* __restrict__ rank)
{
    int pt = blockIdx.x * 256 + threadIdx.x;
    int b = pt >> 13, n = pt & 8191;
    float4 p = xyzw[pt];
    int cell = morton_cell(p.x, p.y, p.z);
    int dst = atomicAdd(&off[b * NCELL + cell], 1);
    sx4[(b << 13) + dst] = p;
    sid[(b << 13) + dst] = n;
    rank[pt] = dst;
}

// Per-chunk bbox over 256 sorted points. block = chunk (0..127 global).
__global__ __launch_bounds__(256) void k_bbox(
    const float4* __restrict__ sx4, float4* __restrict__ bbmin, float4* __restrict__ bbmax)
{
    __shared__ float smn[4][3], smx[4][3];
    int ch = blockIdx.x, t = threadIdx.x, lane = t & 63, wl = t >> 6;
    float4 p = sx4[ch * 256 + t];
    float mnx = p.x, mny = p.y, mnz = p.z, mxx = p.x, mxy = p.y, mxz = p.z;
#pragma unroll
    for (int o = 32; o >= 1; o >>= 1) {
        mnx = fminf(mnx, __shfl_xor(mnx, o, 64)); mxx = fmaxf(mxx, __shfl_xor(mxx, o, 64));
        mny = fminf(mny, __shfl_xor(mny, o, 64)); mxy = fmaxf(mxy, __shfl_xor(mxy, o, 64));
        mnz = fminf(mnz, __shfl_xor(mnz, o, 64)); mxz = fmaxf(mxz, __shfl_xor(mxz, o, 64));
    }
    if (lane == 0) { smn[wl][0]=mnx; smn[wl][1]=mny; smn[wl][2]=mnz;
                     smx[wl][0]=mxx; smx[wl][1]=mxy; smx[wl][2]=mxz; }
    __syncthreads();
    if (t == 0) {
        float a0=smn[0][0], a1=smn[0][1], a2=smn[0][2];
        float b0=smx[0][0], b1=smx[0][1], b2=smx[0][2];
        for (int w = 1; w < 4; w++) {
            a0=fminf(a0,smn[w][0]); a1=fminf(a1,smn[w][1]); a2=fminf(a2,smn[w][2]);
            b0=fmaxf(b0,smx[w][0]); b1=fmaxf(b1,smx[w][1]); b2=fmaxf(b2,smx[w][2]);
        }
        bbmin[ch] = make_float4(a0,a1,a2,0.f);
        bbmax[ch] = make_float4(b0,b1,b2,0.f);
    }
}

// Wave-cooperative KNN with warm-start window sort + bbox chunk pruning.
// One query (sorted order) per wave; outputs SORTED-space candidate ids.
__global__ __launch_bounds__(256) void k_knn(
    const float4* __restrict__ sx4,
    const float4* __restrict__ bbmin, const float4* __restrict__ bbmax,
    int* __restrict__ pip)
{
    __shared__ float lx[256], ly[256], lz[256], lw[256];
    __shared__ unsigned int wmask[4];
    int t = threadIdx.x, lane = t & 63, wl = t >> 6;
    int gq = blockIdx.x * 4 + wl;
    int b = __builtin_amdgcn_readfirstlane(gq >> 13);
    int qs = gq & 8191;
    const float4* sb = sx4 + ((size_t)b << 13);
    float4 me = sb[qs];                       // wave-uniform
    const float INF = 3.402823466e38f;

    // phase 1: sort the 64-point positional window (spatially local -> warm tau)
    int ws0 = qs - 32; ws0 = ws0 < 0 ? 0 : (ws0 > (NN - 64) ? (NN - 64) : ws0);
    float4 cp = sb[ws0 + lane];
    int cid = ws0 + lane;                     // sorted-space id
    float d = distf(me, cp.x, cp.y, cp.z, cp.w);
#pragma unroll
    for (int k2 = 2; k2 <= 64; k2 <<= 1) {
#pragma unroll
        for (int j2 = k2 >> 1; j2 >= 1; j2 >>= 1) {
            float od = __shfl_xor(d, j2, 64);
            int   oi = __shfl_xor(cid, j2, 64);
            bool up = ((lane & k2) == 0);
            bool lower = ((lane & j2) == 0);
            bool wantMin = (lower == up);
            bool to = wantMin ? (od < d) : (od > d);
            d = to ? od : d; cid = to ? oi : cid;
        }
    }
    bool lt32 = (lane < 32);
    float val = lt32 ? d : INF;
    int vid = cid;
    float tau = __int_as_float(__builtin_amdgcn_readlane(__float_as_int(val), 31));

    // phase 2a: chunk mask vs warm tau
    unsigned int m32 = 0;
    for (int c = 0; c < NCHUNK; c++) {
        float md = mind2(me, bbmin[b * NCHUNK + c], bbmax[b * NCHUNK + c]);
        if (md <= tau * 1.0001f + 1e-5f) m32 |= (1u << c);
    }
    if (lane == 0) wmask[wl] = m32;
    __syncthreads();
    unsigned int bm = wmask[0] | wmask[1] | wmask[2] | wmask[3];  // block-uniform

    // phase 2b: scan surviving chunks (window positions excluded -> no dups)
    while (bm) {
        int c = __builtin_ctz(bm); bm &= bm - 1;
        __syncthreads();
        {
            float4 p = sb[c * 256 + t];
            lx[t] = p.x; ly[t] = p.y; lz[t] = p.z; lw[t] = p.w;
        }
        __syncthreads();
        float md = mind2(me, bbmin[b * NCHUNK + c], bbmax[b * NCHUNK + c]);
        if (md <= tau * 1.0001f + 1e-5f) {
#pragma unroll 2
            for (int s = 0; s < 4; s++) {
                int ci = s * 64 + lane;
                int pos = c * 256 + ci;
                float dd = distf(me, lx[ci], ly[ci], lz[ci], lw[ci]);
                bool inwin = (pos >= ws0) && (pos < ws0 + 64);
                dd = inwin ? INF : dd;
                unsigned long long m = __ballot(dd < tau);
                while (m) {
                    int hl = __builtin_ctzll(m); m &= m - 1;
                    float dn = __int_as_float(
                        __builtin_amdgcn_readlane(__float_as_int(dd), hl));
                    int jn = c * 256 + s * 64 + hl;   // sorted-space id (scalar)
                    unsigned long long bl = __ballot(val < dn);
                    int pos2 = __popcll(bl);
                    float sv = __shfl_up(val, 1, 64);
                    int   sj = __shfl_up(vid, 1, 64);
                    float nv = (lane > pos2) ? sv : val; nv = (lane == pos2) ? dn : nv;
                    int   nj = (lane > pos2) ? sj : vid; nj = (lane == pos2) ? jn : nj;
                    val = lt32 ? nv : val;
                    vid = lt32 ? nj : vid;
                    tau = __int_as_float(__builtin_amdgcn_readlane(__float_as_int(val), 31));
                }
            }
        }
    }
    if (lt32) pip[(size_t)gq * NCAND + lane] = vid;
}

// Exact refinement in SORTED space: fp64 distances for 32 candidates,
// top-16 by (d, ORIGINAL index) lexicographic. Outputs sorted-space ids.
__global__ __launch_bounds__(256) void k_refine(
    const float4* __restrict__ sx4, const int* __restrict__ sid,
    const int* __restrict__ pip, int* __restrict__ idx)
{
    int gq = blockIdx.x * 256 + threadIdx.x;
    int b = gq >> 13;
    const float4* sb = sx4 + ((size_t)b << 13);
    const int* ib = sid + ((size_t)b << 13);
    float4 mef = sb[gq & 8191];
    double mx = (double)mef.x, my = (double)mef.y, mz = (double)mef.z;
    double msq = (mx * mx + my * my) + mz * mz;
    double bd[16]; int bi[16]; int bo[16];
#pragma unroll
    for (int s = 0; s < 16; s++) { bd[s] = 1e300; bi[s] = 0; bo[s] = 0x7fffffff; }
    for (int c = 0; c < NCAND; c++) {
        int j = pip[(size_t)gq * NCAND + c];
        float4 cj = sb[j];
        int oj = ib[j];
        double jx = (double)cj.x, jy = (double)cj.y, jz = (double)cj.z;
        double dot = (mx * jx + my * jy) + mz * jz;
        double sqj = (jx * jx + jy * jy) + jz * jz;
        double dd = (-2.0 * dot + msq) + sqj;
        if (dd < bd[15] || (dd == bd[15] && oj < bo[15])) {
            double pd_ = dd; int pi_ = j; int po_ = oj;
#pragma unroll
            for (int s = 15; s >= 1; s--) {
                bool cc = (pd_ < bd[s - 1]) || (pd_ == bd[s - 1] && po_ < bo[s - 1]);
                double nd = cc ? bd[s - 1] : pd_;  int ni = cc ? bi[s - 1] : pi_;  int no = cc ? bo[s - 1] : po_;
                double npd = cc ? pd_ : bd[s - 1]; int npi = cc ? pi_ : bi[s - 1]; int npo = cc ? po_ : bo[s - 1];
                bd[s] = nd; bi[s] = ni; bo[s] = no; pd_ = npd; pi_ = npi; po_ = npo;
            }
            bd[0] = pd_; bi[0] = pi_; bo[0] = po_;
        }
    }
#pragma unroll
    for (int s = 0; s < 16; s++) idx[(size_t)gq * 16 + s] = bi[s];
}

// Per-point GEMVs, output scattered to SORTED layout via rank.
__global__ __launch_bounds__(256) void k_F(
    const float* __restrict__ feats, const float* __restrict__ b1, const float* __restrict__ bv,
    const float* __restrict__ pw1aT, const float* __restrict__ pw1bT, const float* __restrict__ pwvaT,
    const int* __restrict__ rank,
    float* __restrict__ F1, float* __restrict__ F2, float* __restrict__ FV)
{
    int t = threadIdx.x;
    int lane = t & 63;
    int wave = t >> 6;
    int pt0 = blockIdx.x * 64 + wave * 16;
    int b   = __builtin_amdgcn_readfirstlane(pt0 >> 13);
    int n0  = __builtin_amdgcn_readfirstlane(pt0 & 8191);
    const float* fb = feats + (size_t)b * CC * NN;
    float accA[16], accB[16], accV[16];
    float bb1 = b1[lane], bbv = bv[lane];
#pragma unroll
    for (int p = 0; p < 16; p++) { accA[p] = bb1; accB[p] = 0.f; accV[p] = bbv; }
    for (int c = 0; c < 64; c++) {
        float wA = pw1aT[c * 64 + lane];
        float wB = pw1bT[c * 64 + lane];
        float wV = pwvaT[c * 64 + lane];
        const float* fr = fb + (size_t)c * NN + n0;
#pragma unroll
        for (int p = 0; p < 16; p++) {
            float f = fr[p];
            accA[p] = fmaf(wA, f, accA[p]);
            accB[p] = fmaf(wB, f, accB[p]);
            accV[p] = fmaf(wV, f, accV[p]);
        }
    }
#pragma unroll
    for (int p = 0; p < 16; p++) {
        int dst = (b << 13) + rank[pt0 + p];     // wave-uniform scalar
        F1[(size_t)dst * 64 + lane] = accA[p];
        F2[(size_t)dst * 64 + lane] = accB[p];
        FV[(size_t)dst * 64 + lane] = accV[p];
    }
}

// BN stats pass over all (pt,k) in SORTED space (local gathers).
__global__ __launch_bounds__(256) void k_hv(
    const float4* __restrict__ sx4, const int* __restrict__ idx,
    const float* __restrict__ F1, const float* __restrict__ F2, const float* __restrict__ FV,
    const float* __restrict__ relw, float* __restrict__ stats)
{
    __shared__ float red[4][4][64];
    int t = threadIdx.x;
    int lane = t & 63;
    int wl = t >> 6;
    int w = blockIdx.x * 4 + wl;   // 0..8191
    float rw0 = relw[0 * 64 + lane], rw1 = relw[1 * 64 + lane], rw2 = relw[2 * 64 + lane];
    float rw3 = relw[3 * 64 + lane], rw4 = relw[4 * 64 + lane], rw5 = relw[5 * 64 + lane];
    float sh = 0.f, sh2 = 0.f, sv = 0.f, sv2 = 0.f;
    for (int i = 0; i < 4; i++) {
        int gq = __builtin_amdgcn_readfirstlane(w + i * 8192);   // sorted-global
        int b = gq >> 13;
        const float4* sb = sx4 + ((size_t)b << 13);
        float4 me = sb[gq & 8191];
        float F1v = F1[(size_t)gq * 64 + lane];
        const int* ip = idx + (size_t)gq * 16;
#pragma unroll
        for (int k = 0; k < 16; k++) {
            int g = (b << 13) + ip[k];           // sorted-global neighbor
            float4 cj = sb[ip[k]];
            float rx = cj.x - me.x, ry = cj.y - me.y, rz = cj.z - me.z;
            float h = F1v + F2[(size_t)g * 64 + lane];
            h = fmaf(rw0, rx, h); h = fmaf(rw1, ry, h); h = fmaf(rw2, rz, h);
            float v = FV[(size_t)g * 64 + lane];
            v = fmaf(rw3, rx, v); v = fmaf(rw4, ry, v); v = fmaf(rw5, rz, v);
            sh += h; sh2 = fmaf(h, h, sh2);
            sv += v; sv2 = fmaf(v, v, sv2);
        }
    }
    red[0][wl][lane] = sh; red[1][wl][lane] = sh2;
    red[2][wl][lane] = sv; red[3][wl][lane] = sv2;
    __syncthreads();
    // wave wl reduces array wl and issues one atomic
    float s = red[wl][0][lane] + red[wl][1][lane] + red[wl][2][lane] + red[wl][3][lane];
    atomicAdd(&stats[wl * 64 + lane], s);
}

// Attention in SORTED space; opre scattered back to ORIGINAL layout.
__global__ __launch_bounds__(256) void k_attn(
    const float4* __restrict__ sx4, const int* __restrict__ sid,
    const int* __restrict__ idx,
    const float* __restrict__ F1, const float* __restrict__ F2, const float* __restrict__ FV,
    const float* __restrict__ relw, float* __restrict__ stats,
    const float* __restrict__ g1, const float* __restrict__ be1,
    const float* __restrict__ W2, const float* __restrict__ b2,
    const float* __restrict__ gv, const float* __restrict__ bev,
    const float* __restrict__ pwoT, const float* __restrict__ bo,
    float* __restrict__ opre)
{
    __shared__ float lds_out[4][64];
    __shared__ float ro[4][64], ro2[4][64];
    int t = threadIdx.x;
    int lane = t & 63;
    int wl = t >> 6;
    int gq = blockIdx.x * 4 + wl;            // sorted-global query
    const float invM = 1.f / 524288.f;
    float hm = stats[lane] * invM, hq = stats[64 + lane] * invM;
    float s1 = g1[lane] * rsqrtf(hq - hm * hm + EPSBN);
    float t1 = be1[lane] - s1 * hm;
    float vm = stats[128 + lane] * invM, vq = stats[192 + lane] * invM;
    float sv = gv[lane] * rsqrtf(vq - vm * vm + EPSBN);
    float tv = bev[lane] - sv * vm;
    float rw0 = relw[0 * 64 + lane], rw1 = relw[1 * 64 + lane], rw2 = relw[2 * 64 + lane];
    float rw3 = relw[3 * 64 + lane], rw4 = relw[4 * 64 + lane], rw5 = relw[5 * 64 + lane];
    float w2v = W2[lane];
    float b2v = b2[0];
    float bov = bo[lane];

    int b = __builtin_amdgcn_readfirstlane(gq >> 13);
    const float4* sb = sx4 + ((size_t)b << 13);
    float4 me = sb[gq & 8191];
    float F1v = F1[(size_t)gq * 64 + lane];
    const int* ip = idx + (size_t)gq * 16;
    float ek[16], vk[16];
#pragma unroll
    for (int k = 0; k < 16; k++) {
        int gl = ip[k];                       // wave-uniform scalar
        int g = (b << 13) + gl;
        float4 cj = sb[gl];
        float rx = cj.x - me.x, ry = cj.y - me.y, rz = cj.z - me.z;
        float h = F1v + F2[(size_t)g * 64 + lane];
        h = fmaf(rw0, rx, h); h = fmaf(rw1, ry, h); h = fmaf(rw2, rz, h);
        float a = fmaxf(fmaf(s1, h, t1), 0.f);
        float v = FV[(size_t)g * 64 + lane];
        v = fmaf(rw3, rx, v); v = fmaf(rw4, ry, v); v = fmaf(rw5, rz, v);
        vk[k] = fmaxf(fmaf(sv, v, tv), 0.f);
        float lg = w2v * a;
#pragma unroll
        for (int off = 32; off >= 1; off >>= 1) lg += __shfl_xor(lg, off, 64);
        ek[k] = lg + b2v;
    }
    float mx = ek[0];
#pragma unroll
    for (int k = 1; k < 16; k++) mx = fmaxf(mx, ek[k]);
    float ssum = 0.f;
#pragma unroll
    for (int k = 0; k < 16; k++) { float e = __expf(ek[k] - mx); ek[k] = e; ssum += e; }
    float acc = 0.f;
#pragma unroll
    for (int k = 0; k < 16; k++) acc = fmaf(ek[k], vk[k], acc);
    float outv = acc / ssum;

    lds_out[wl][lane] = outv;
    __syncthreads();
    float op = bov;
    for (int c = 0; c < 64; c++)
        op = fmaf(pwoT[c * 64 + lane], lds_out[wl][c], op);
    int orig = (b << 13) + sid[gq];           // wave-uniform scalar
    opre[(size_t)orig * 64 + lane] = op;
    ro[wl][lane] = op; ro2[wl][lane] = op * op;
    __syncthreads();
    if (wl == 0) {
        float s = ro[0][lane] + ro[1][lane] + ro[2][lane] + ro[3][lane];
        atomicAdd(&stats[256 + lane], s);
    } else if (wl == 1) {
        float s = ro2[0][lane] + ro2[1][lane] + ro2[2][lane] + ro2[3][lane];
        atomicAdd(&stats[320 + lane], s);
    }
}

// Final: BN(o)+relu + residual feats, transpose [B,N,C]->[B,C,N]
__global__ __launch_bounds__(256) void k_final(
    const float* __restrict__ opre, const float* __restrict__ stats,
    const float* __restrict__ go, const float* __restrict__ beo,
    const float* __restrict__ feats, float* __restrict__ out)
{
    __shared__ float tile[64][65];
    int t = threadIdx.x;
    int blk = blockIdx.x;
    int b = blk >> 7, n0 = (blk & 127) << 6;
#pragma unroll
    for (int i = 0; i < 16; i++) {
        int e = t + i * 256;
        int r = e >> 6, c = e & 63;
        tile[r][c] = opre[((size_t)((b << 13) + n0 + r)) * 64 + c];
    }
    __syncthreads();
    const float invM = 1.f / 32768.f;
    int lane = t & 63, wv = t >> 6;
#pragma unroll
    for (int i = 0; i < 16; i++) {
        int c = wv * 16 + i;
        float om = stats[256 + c] * invM, oq = stats[320 + c] * invM;
        float so = go[c] * rsqrtf(oq - om * om + EPSBN);
        float to = beo[c] - so * om;
        float val = fmaxf(fmaf(so, tile[lane][c], to), 0.f);
        size_t oix = ((size_t)b * 64 + c) * NN + n0 + lane;
        out[oix] = val + feats[oix];
    }
}

extern "C" void kernel_launch(void* const* d_in, const int* in_sizes, int n_in,
                              void* d_out, int out_size, void* d_ws, size_t ws_size,
                              hipStream_t stream)
{
    const float* xyz  = (const float*)d_in[0];
    const float* feats= (const float*)d_in[1];
    const float* W1   = (const float*)d_in[2];
    const float* b1   = (const float*)d_in[3];
    const float* g1   = (const float*)d_in[4];
    const float* be1  = (const float*)d_in[5];
    const float* W2   = (const float*)d_in[6];
    const float* b2   = (const float*)d_in[7];
    const float* Wv   = (const float*)d_in[8];
    const float* bv   = (const float*)d_in[9];
    const float* gv   = (const float*)d_in[10];
    const float* bev  = (const float*)d_in[11];
    const float* Wo   = (const float*)d_in[12];
    const float* bo   = (const float*)d_in[13];
    const float* go   = (const float*)d_in[14];
    const float* beo  = (const float*)d_in[15];

    float* ws = (float*)d_ws;
    float* xyzw  = ws + OFF_XYZW;
    float* pw1aT = ws + OFF_PW1AT;
    float* pw1bT = ws + OFF_PW1BT;
    float* pwvaT = ws + OFF_PWVAT;
    float* pwoT  = ws + OFF_PWOT;
    float* relw  = ws + OFF_RELW;
    float* stats = ws + OFF_STATS;
    int*   idx   = (int*)(ws + OFF_IDX);
    int*   pip   = (int*)(ws + OFF_PIP);
    float4* sx4  = (float4*)(ws + OFF_SX4);
    int*   sid   = (int*)(ws + OFF_SID);
    int*   hist  = (int*)(ws + OFF_HIST);
    float4* bbmn = (float4*)(ws + OFF_BB);
    float4* bbmx = (float4*)(ws + OFF_BB + 512);
    int*   rank  = (int*)(ws + OFF_RANK);
    float* F1    = ws + OFF_F1;
    float* F2    = ws + OFF_F2;
    float* FV    = ws + OFF_FV;
    float* opre  = ws + OFF_OPRE;   // aliases pip (dead after k_refine)

    k_zero<<<1, 256, 0, stream>>>(hist);
    k_prep<<<129, 256, 0, stream>>>(xyz, W1, Wv, Wo, xyzw, hist,
                                    pw1aT, pw1bT, pwvaT, pwoT, relw, stats);
    k_scan<<<4, 256, 0, stream>>>(hist);
    k_scatter<<<128, 256, 0, stream>>>((const float4*)xyzw, hist, sx4, sid, rank);
    k_bbox<<<128, 256, 0, stream>>>((const float4*)sx4, bbmn, bbmx);
    k_F<<<512, 256, 0, stream>>>(feats, b1, bv, pw1aT, pw1bT, pwvaT, rank, F1, F2, FV);
    k_knn<<<8192, 256, 0, stream>>>((const float4*)sx4, bbmn, bbmx, pip);
    k_refine<<<128, 256, 0, stream>>>((const float4*)sx4, sid, pip, idx);
    k_hv<<<2048, 256, 0, stream>>>((const float4*)sx4, idx, F1, F2, FV, relw, stats);
    k_attn<<<8192, 256, 0, stream>>>((const float4*)sx4, sid, idx, F1, F2, FV, relw, stats,
                                     g1, be1, W2, b2, gv, bev, pwoT, bo, opre);
    k_final<<<512, 256, 0, stream>>>(opre, stats, go, beo, feats, (float*)d_out);
}

// Round 8
// 579.798 us; speedup vs baseline: 2.0313x; 1.0034x over previous
//
#include <hip/hip_runtime.h>
#include <math.h>

// Problem constants
#define BB 4
#define NN 8192
#define CC 64
#define KK 16
#define HH 64
#define NPTS (BB*NN)   // 32768
#define EPSBN 1e-5f
#define NCAND 32       // fp32 prefilter keeps top-32; fp64 refine picks 16
#define NCELL 4096     // 16^3 Morton cells
#define NCHUNK 32      // 256-point chunks per batch

// ---------------- ws layout (float offsets) ----------------
#define OFF_XYZW  0
#define OFF_PW1AT 131072
#define OFF_PW1BT 135168
#define OFF_PWVAT 139264
#define OFF_PWOT  143360
#define OFF_RELW  147456
#define OFF_STATS 147840
#define OFF_IDX   148224      // idx: 32768*16 ints (SORTED-space neighbor ids)
#define OFF_PIP   672512      // pip: 32768*32 ints (sorted-space candidates)
#define OFF_OPRE  672512      // OPRE aliases PIP (dead after k_refine)
#define OFF_SX4   2769664     // sorted xyzw [4][8192] float4
#define OFF_SID   2900736     // sorted->orig ids [4][8192] int
#define OFF_HIST  2933504     // [4][4096] int
#define OFF_BB    2949888     // bbmin[128] f4 + bbmax[128] f4
#define OFF_RANK  2950912     // orig->sorted rank [4][8192] int
#define OFF_F1    4866816     // SORTED layout
#define OFF_F2    6963968     // SORTED layout
#define OFF_FV    9061120     // SORTED layout

__device__ __forceinline__ int morton_cell(float x, float y, float z) {
    int cx = (int)floorf((x + 4.f) * 2.f);
    int cy = (int)floorf((y + 4.f) * 2.f);
    int cz = (int)floorf((z + 4.f) * 2.f);
    cx = cx < 0 ? 0 : (cx > 15 ? 15 : cx);
    cy = cy < 0 ? 0 : (cy > 15 ? 15 : cy);
    cz = cz < 0 ? 0 : (cz > 15 ? 15 : cz);
    int ex = (cx & 1) | ((cx & 2) << 2) | ((cx & 4) << 4) | ((cx & 8) << 6);
    int ey = (cy & 1) | ((cy & 2) << 2) | ((cy & 4) << 4) | ((cy & 8) << 6);
    int ez = (cz & 1) | ((cz & 2) << 2) | ((cz & 4) << 4) | ((cz & 8) << 6);
    return ex | (ey << 1) | (ez << 2);
}

__device__ __forceinline__ float distf(float4 me, float jx, float jy, float jz, float jw) {
    float dot = fmaf(me.z, jz, fmaf(me.y, jy, me.x * jx));
    return fmaf(-2.f, dot, me.w) + jw;
}

__device__ __forceinline__ float mind2(float4 me, float4 bmin, float4 bmax) {
    float dx = fmaxf(fmaxf(bmin.x - me.x, me.x - bmax.x), 0.f);
    float dy = fmaxf(fmaxf(bmin.y - me.y, me.y - bmax.y), 0.f);
    float dz = fmaxf(fmaxf(bmin.z - me.z, me.z - bmax.z), 0.f);
    return fmaf(dx, dx, fmaf(dy, dy, dz * dz));
}

__global__ __launch_bounds__(256) void k_zero(int* __restrict__ hist) {
    int t = threadIdx.x;
    for (int i = t; i < BB * NCELL; i += 256) hist[i] = 0;
}

__global__ __launch_bounds__(256) void k_prep(
    const float* __restrict__ xyz, const float* __restrict__ W1,
    const float* __restrict__ Wv, const float* __restrict__ Wo,
    float* __restrict__ xyzw, int* __restrict__ hist,
    float* __restrict__ pw1aT, float* __restrict__ pw1bT,
    float* __restrict__ pwvaT, float* __restrict__ pwoT, float* __restrict__ relw,
    float* __restrict__ stats)
{
    int t = threadIdx.x;
    int bid = blockIdx.x;
    if (bid < 128) {
        int pt = bid * 256 + t;
        int b = pt >> 13, n = pt & 8191;
        const float* xb = xyz + (size_t)b * 3 * NN;
        float x = xb[n], y = xb[NN + n], z = xb[2 * NN + n];
        float sq = __fadd_rn(__fadd_rn(__fmul_rn(x, x), __fmul_rn(y, y)), __fmul_rn(z, z));
        ((float4*)xyzw)[pt] = make_float4(x, y, z, sq);
        atomicAdd(&hist[b * NCELL + morton_cell(x, y, z)], 1);
    } else {
        for (int e = t; e < 4096; e += 256) {
            int c = e >> 6, o = e & 63;
            pw1aT[e] = W1[o * 131 + c];
            pw1bT[e] = W1[o * 131 + 64 + c];
            pwvaT[e] = Wv[o * 67 + c];
            pwoT[e]  = Wo[o * 64 + c];
        }
        for (int e = t; e < 384; e += 256) {
            int d = e >> 6, o = e & 63;
            relw[e] = (d < 3) ? W1[o * 131 + 128 + d] : Wv[o * 67 + 64 + (d - 3)];
            stats[e] = 0.0f;
        }
    }
}

// Exclusive scan of per-batch 4096-bin histogram (in place), one block per batch.
__global__ __launch_bounds__(256) void k_scan(int* __restrict__ hist) {
    __shared__ int part[256];
    int b = blockIdx.x, t = threadIdx.x;
    int* h = hist + b * NCELL;
    int loc[16]; int s = 0;
#pragma unroll
    for (int i = 0; i < 16; i++) { loc[i] = h[t * 16 + i]; s += loc[i]; }
    part[t] = s;
    __syncthreads();
    for (int off = 1; off < 256; off <<= 1) {
        int v = (t >= off) ? part[t - off] : 0;
        __syncthreads();
        part[t] += v;
        __syncthreads();
    }
    int run = (t > 0) ? part[t - 1] : 0;
#pragma unroll
    for (int i = 0; i < 16; i++) { int c = loc[i]; h[t * 16 + i] = run; run += c; }
}

__global__ __launch_bounds__(256) void k_scatter(
    const float4* __restrict__ xyzw, int* __restrict__ off,
    float4* __restrict__ sx4, int* __restrict__ sid, int* __restrict__ rank)
{
    int pt = blockIdx.x * 256 + threadIdx.x;
    int b = pt >> 13, n = pt & 8191;
    float4 p = xyzw[pt];
    int cell = morton_cell(p.x, p.y, p.z);
    int dst = atomicAdd(&off[b * NCELL + cell], 1);
    sx4[(b << 13) + dst] = p;
    sid[(b << 13) + dst] = n;
    rank[pt] = dst;
}

// Per-chunk bbox over 256 sorted points. block = chunk (0..127 global).
__global__ __launch_bounds__(256) void k_bbox(
    const float4* __restrict__ sx4, float4* __restrict__ bbmin, float4* __restrict__ bbmax)
{
    __shared__ float smn[4][3], smx[4][3];
    int ch = blockIdx.x, t = threadIdx.x, lane = t & 63, wl = t >> 6;
    float4 p = sx4[ch * 256 + t];
    float mnx = p.x, mny = p.y, mnz = p.z, mxx = p.x, mxy = p.y, mxz = p.z;
#pragma unroll
    for (int o = 32; o >= 1; o >>= 1) {
        mnx = fminf(mnx, __shfl_xor(mnx, o, 64)); mxx = fmaxf(mxx, __shfl_xor(mxx, o, 64));
        mny = fminf(mny, __shfl_xor(mny, o, 64)); mxy = fmaxf(mxy, __shfl_xor(mxy, o, 64));
        mnz = fminf(mnz, __shfl_xor(mnz, o, 64)); mxz = fmaxf(mxz, __shfl_xor(mxz, o, 64));
    }
    if (lane == 0) { smn[wl][0]=mnx; smn[wl][1]=mny; smn[wl][2]=mnz;
                     smx[wl][0]=mxx; smx[wl][1]=mxy; smx[wl][2]=mxz; }
    __syncthreads();
    if (t == 0) {
        float a0=smn[0][0], a1=smn[0][1], a2=smn[0][2];
        float b0=smx[0][0], b1=smx[0][1], b2=smx[0][2];
        for (int w = 1; w < 4; w++) {
            a0=fminf(a0,smn[w][0]); a1=fminf(a1,smn[w][1]); a2=fminf(a2,smn[w][2]);
            b0=fmaxf(b0,smx[w][0]); b1=fmaxf(b1,smx[w][1]); b2=fmaxf(b2,smx[w][2]);
        }
        bbmin[ch] = make_float4(a0,a1,a2,0.f);
        bbmax[ch] = make_float4(b0,b1,b2,0.f);
    }
}

// Wave-cooperative KNN with warm-start window sort + bbox chunk pruning.
__global__ __launch_bounds__(256) void k_knn(
    const float4* __restrict__ sx4,
    const float4* __restrict__ bbmin, const float4* __restrict__ bbmax,
    int* __restrict__ pip)
{
    __shared__ float lx[256], ly[256], lz[256], lw[256];
    __shared__ unsigned int wmask[4];
    int t = threadIdx.x, lane = t & 63, wl = t >> 6;
    int gq = blockIdx.x * 4 + wl;
    int b = __builtin_amdgcn_readfirstlane(gq >> 13);
    int qs = gq & 8191;
    const float4* sb = sx4 + ((size_t)b << 13);
    float4 me = sb[qs];                       // wave-uniform
    const float INF = 3.402823466e38f;

    // phase 1: sort the 64-point positional window (spatially local -> warm tau)
    int ws0 = qs - 32; ws0 = ws0 < 0 ? 0 : (ws0 > (NN - 64) ? (NN - 64) : ws0);
    float4 cp = sb[ws0 + lane];
    int cid = ws0 + lane;                     // sorted-space id
    float d = distf(me, cp.x, cp.y, cp.z, cp.w);
#pragma unroll
    for (int k2 = 2; k2 <= 64; k2 <<= 1) {
#pragma unroll
        for (int j2 = k2 >> 1; j2 >= 1; j2 >>= 1) {
            float od = __shfl_xor(d, j2, 64);
            int   oi = __shfl_xor(cid, j2, 64);
            bool up = ((lane & k2) == 0);
            bool lower = ((lane & j2) == 0);
            bool wantMin = (lower == up);
            bool to = wantMin ? (od < d) : (od > d);
            d = to ? od : d; cid = to ? oi : cid;
        }
    }
    bool lt32 = (lane < 32);
    float val = lt32 ? d : INF;
    int vid = cid;
    float tau = __int_as_float(__builtin_amdgcn_readlane(__float_as_int(val), 31));

    // phase 2a: chunk mask vs warm tau
    unsigned int m32 = 0;
    for (int c = 0; c < NCHUNK; c++) {
        float md = mind2(me, bbmin[b * NCHUNK + c], bbmax[b * NCHUNK + c]);
        if (md <= tau * 1.0001f + 1e-5f) m32 |= (1u << c);
    }
    if (lane == 0) wmask[wl] = m32;
    __syncthreads();
    unsigned int bm = wmask[0] | wmask[1] | wmask[2] | wmask[3];  // block-uniform

    // phase 2b: scan surviving chunks (window positions excluded -> no dups)
    while (bm) {
        int c = __builtin_ctz(bm); bm &= bm - 1;
        __syncthreads();
        {
            float4 p = sb[c * 256 + t];
            lx[t] = p.x; ly[t] = p.y; lz[t] = p.z; lw[t] = p.w;
        }
        __syncthreads();
        float md = mind2(me, bbmin[b * NCHUNK + c], bbmax[b * NCHUNK + c]);
        if (md <= tau * 1.0001f + 1e-5f) {
#pragma unroll 2
            for (int s = 0; s < 4; s++) {
                int ci = s * 64 + lane;
                int pos = c * 256 + ci;
                float dd = distf(me, lx[ci], ly[ci], lz[ci], lw[ci]);
                bool inwin = (pos >= ws0) && (pos < ws0 + 64);
                dd = inwin ? INF : dd;
                unsigned long long m = __ballot(dd < tau);
                while (m) {
                    int hl = __builtin_ctzll(m); m &= m - 1;
                    float dn = __int_as_float(
                        __builtin_amdgcn_readlane(__float_as_int(dd), hl));
                    int jn = c * 256 + s * 64 + hl;   // sorted-space id (scalar)
                    unsigned long long bl = __ballot(val < dn);
                    int pos2 = __popcll(bl);
                    float sv = __shfl_up(val, 1, 64);
                    int   sj = __shfl_up(vid, 1, 64);
                    float nv = (lane > pos2) ? sv : val; nv = (lane == pos2) ? dn : nv;
                    int   nj = (lane > pos2) ? sj : vid; nj = (lane == pos2) ? jn : nj;
                    val = lt32 ? nv : val;
                    vid = lt32 ? nj : vid;
                    tau = __int_as_float(__builtin_amdgcn_readlane(__float_as_int(val), 31));
                }
            }
        }
    }
    if (lt32) pip[(size_t)gq * NCAND + lane] = vid;
}

// Exact refinement in SORTED space: fp64 distances for 32 candidates,
// top-16 by (d, ORIGINAL index). Outputs sorted-space ids.
__global__ __launch_bounds__(256) void k_refine(
    const float4* __restrict__ sx4, const int* __restrict__ sid,
    const int* __restrict__ pip, int* __restrict__ idx)
{
    int gq = blockIdx.x * 256 + threadIdx.x;
    int b = gq >> 13;
    const float4* sb = sx4 + ((size_t)b << 13);
    const int* ib = sid + ((size_t)b << 13);
    float4 mef = sb[gq & 8191];
    double mx = (double)mef.x, my = (double)mef.y, mz = (double)mef.z;
    double msq = (mx * mx + my * my) + mz * mz;
    double bd[16]; int bi[16]; int bo[16];
#pragma unroll
    for (int s = 0; s < 16; s++) { bd[s] = 1e300; bi[s] = 0; bo[s] = 0x7fffffff; }
    for (int c = 0; c < NCAND; c++) {
        int j = pip[(size_t)gq * NCAND + c];
        float4 cj = sb[j];
        int oj = ib[j];
        double jx = (double)cj.x, jy = (double)cj.y, jz = (double)cj.z;
        double dot = (mx * jx + my * jy) + mz * jz;
        double sqj = (jx * jx + jy * jy) + jz * jz;
        double dd = (-2.0 * dot + msq) + sqj;
        if (dd < bd[15] || (dd == bd[15] && oj < bo[15])) {
            double pd_ = dd; int pi_ = j; int po_ = oj;
#pragma unroll
            for (int s = 15; s >= 1; s--) {
                bool cc = (pd_ < bd[s - 1]) || (pd_ == bd[s - 1] && po_ < bo[s - 1]);
                double nd = cc ? bd[s - 1] : pd_;  int ni = cc ? bi[s - 1] : pi_;  int no = cc ? bo[s - 1] : po_;
                double npd = cc ? pd_ : bd[s - 1]; int npi = cc ? pi_ : bi[s - 1]; int npo = cc ? po_ : bo[s - 1];
                bd[s] = nd; bi[s] = ni; bo[s] = no; pd_ = npd; pi_ = npi; po_ = npo;
            }
            bd[0] = pd_; bi[0] = pi_; bo[0] = po_;
        }
    }
#pragma unroll
    for (int s = 0; s < 16; s++) idx[(size_t)gq * 16 + s] = bi[s];
}

// Per-point GEMVs, output scattered to SORTED layout via rank.
__global__ __launch_bounds__(256) void k_F(
    const float* __restrict__ feats, const float* __restrict__ b1, const float* __restrict__ bv,
    const float* __restrict__ pw1aT, const float* __restrict__ pw1bT, const float* __restrict__ pwvaT,
    const int* __restrict__ rank,
    float* __restrict__ F1, float* __restrict__ F2, float* __restrict__ FV)
{
    int t = threadIdx.x;
    int lane = t & 63;
    int wave = t >> 6;
    int pt0 = blockIdx.x * 64 + wave * 16;
    int b   = __builtin_amdgcn_readfirstlane(pt0 >> 13);
    int n0  = __builtin_amdgcn_readfirstlane(pt0 & 8191);
    const float* fb = feats + (size_t)b * CC * NN;
    float accA[16], accB[16], accV[16];
    float bb1 = b1[lane], bbv = bv[lane];
#pragma unroll
    for (int p = 0; p < 16; p++) { accA[p] = bb1; accB[p] = 0.f; accV[p] = bbv; }
    for (int c = 0; c < 64; c++) {
        float wA = pw1aT[c * 64 + lane];
        float wB = pw1bT[c * 64 + lane];
        float wV = pwvaT[c * 64 + lane];
        const float* fr = fb + (size_t)c * NN + n0;
#pragma unroll
        for (int p = 0; p < 16; p++) {
            float f = fr[p];
            accA[p] = fmaf(wA, f, accA[p]);
            accB[p] = fmaf(wB, f, accB[p]);
            accV[p] = fmaf(wV, f, accV[p]);
        }
    }
#pragma unroll
    for (int p = 0; p < 16; p++) {
        int dst = (b << 13) + rank[pt0 + p];     // wave-uniform scalar
        F1[(size_t)dst * 64 + lane] = accA[p];
        F2[(size_t)dst * 64 + lane] = accB[p];
        FV[(size_t)dst * 64 + lane] = accV[p];
    }
}

// BN stats pass. XCD-swizzled: each XCD owns a contiguous sorted-query slice
// (~4096 queries -> F-array slice ~3MB fits its private L2). Batched loads
// (8 neighbors) raise memory-level parallelism.
__global__ __launch_bounds__(256) void k_hv(
    const float4* __restrict__ sx4, const int* __restrict__ idx,
    const float* __restrict__ F1, const float* __restrict__ F2, const float* __restrict__ FV,
    const float* __restrict__ relw, float* __restrict__ stats)
{
    __shared__ float red[4][4][64];
    int t = threadIdx.x;
    int lane = t & 63;
    int wl = t >> 6;
    int bx = blockIdx.x;                       // 2048 blocks
    int vb = (bx & 7) * 256 + (bx >> 3);       // XCD-aware swizzle
    float rw0 = relw[0 * 64 + lane], rw1 = relw[1 * 64 + lane], rw2 = relw[2 * 64 + lane];
    float rw3 = relw[3 * 64 + lane], rw4 = relw[4 * 64 + lane], rw5 = relw[5 * 64 + lane];
    float sh = 0.f, sh2 = 0.f, sv = 0.f, sv2 = 0.f;
    for (int i = 0; i < 4; i++) {
        int gq = __builtin_amdgcn_readfirstlane(vb * 16 + wl * 4 + i);  // contiguous
        int b = gq >> 13;
        const float4* sb = sx4 + ((size_t)b << 13);
        float4 me = sb[gq & 8191];
        float F1v = F1[(size_t)gq * 64 + lane];
        const int* ip = idx + (size_t)gq * 16;
#pragma unroll
        for (int kb = 0; kb < 2; kb++) {
            float4 cjA[8]; float f2A[8], fvA[8];
#pragma unroll
            for (int j = 0; j < 8; j++) {
                int gl = ip[kb * 8 + j];
                cjA[j] = sb[gl];
                size_t go = (size_t)((b << 13) + gl) * 64 + lane;
                f2A[j] = F2[go];
                fvA[j] = FV[go];
            }
#pragma unroll
            for (int j = 0; j < 8; j++) {
                float rx = cjA[j].x - me.x, ry = cjA[j].y - me.y, rz = cjA[j].z - me.z;
                float h = F1v + f2A[j];
                h = fmaf(rw0, rx, h); h = fmaf(rw1, ry, h); h = fmaf(rw2, rz, h);
                float v = fvA[j];
                v = fmaf(rw3, rx, v); v = fmaf(rw4, ry, v); v = fmaf(rw5, rz, v);
                sh += h; sh2 = fmaf(h, h, sh2);
                sv += v; sv2 = fmaf(v, v, sv2);
            }
        }
    }
    red[0][wl][lane] = sh; red[1][wl][lane] = sh2;
    red[2][wl][lane] = sv; red[3][wl][lane] = sv2;
    __syncthreads();
    float s = red[wl][0][lane] + red[wl][1][lane] + red[wl][2][lane] + red[wl][3][lane];
    atomicAdd(&stats[wl * 64 + lane], s);
}

// Attention in SORTED space, XCD-swizzled (reuses the L2 slice k_hv warmed);
// batched loads; opre scattered back to ORIGINAL layout.
__global__ __launch_bounds__(256) void k_attn(
    const float4* __restrict__ sx4, const int* __restrict__ sid,
    const int* __restrict__ idx,
    const float* __restrict__ F1, const float* __restrict__ F2, const float* __restrict__ FV,
    const float* __restrict__ relw, float* __restrict__ stats,
    const float* __restrict__ g1, const float* __restrict__ be1,
    const float* __restrict__ W2, const float* __restrict__ b2,
    const float* __restrict__ gv, const float* __restrict__ bev,
    const float* __restrict__ pwoT, const float* __restrict__ bo,
    float* __restrict__ opre)
{
    __shared__ float lds_out[4][64];
    __shared__ float ro[4][64], ro2[4][64];
    int t = threadIdx.x;
    int lane = t & 63;
    int wl = t >> 6;
    int bx = blockIdx.x;                      // 8192 blocks
    int vb = (bx & 7) * 1024 + (bx >> 3);     // XCD-aware swizzle
    int gq = vb * 4 + wl;                     // sorted-global query
    const float invM = 1.f / 524288.f;
    float hm = stats[lane] * invM, hq = stats[64 + lane] * invM;
    float s1 = g1[lane] * rsqrtf(hq - hm * hm + EPSBN);
    float t1 = be1[lane] - s1 * hm;
    float vm = stats[128 + lane] * invM, vq = stats[192 + lane] * invM;
    float sv = gv[lane] * rsqrtf(vq - vm * vm + EPSBN);
    float tv = bev[lane] - sv * vm;
    float rw0 = relw[0 * 64 + lane], rw1 = relw[1 * 64 + lane], rw2 = relw[2 * 64 + lane];
    float rw3 = relw[3 * 64 + lane], rw4 = relw[4 * 64 + lane], rw5 = relw[5 * 64 + lane];
    float w2v = W2[lane];
    float b2v = b2[0];
    float bov = bo[lane];

    int b = __builtin_amdgcn_readfirstlane(gq >> 13);
    const float4* sb = sx4 + ((size_t)b << 13);
    float4 me = sb[gq & 8191];
    float F1v = F1[(size_t)gq * 64 + lane];
    int orig = (b << 13) + sid[gq];           // hoisted wave-uniform scalar
    const int* ip = idx + (size_t)gq * 16;
    float ek[16], vk[16];
#pragma unroll
    for (int kb = 0; kb < 2; kb++) {
        float4 cjA[8]; float f2A[8], fvA[8];
#pragma unroll
        for (int j = 0; j < 8; j++) {
            int gl = ip[kb * 8 + j];
            cjA[j] = sb[gl];
            size_t go = (size_t)((b << 13) + gl) * 64 + lane;
            f2A[j] = F2[go];
            fvA[j] = FV[go];
        }
#pragma unroll
        for (int j = 0; j < 8; j++) {
            int k = kb * 8 + j;
            float rx = cjA[j].x - me.x, ry = cjA[j].y - me.y, rz = cjA[j].z - me.z;
            float h = F1v + f2A[j];
            h = fmaf(rw0, rx, h); h = fmaf(rw1, ry, h); h = fmaf(rw2, rz, h);
            float a = fmaxf(fmaf(s1, h, t1), 0.f);
            float v = fvA[j];
            v = fmaf(rw3, rx, v); v = fmaf(rw4, ry, v); v = fmaf(rw5, rz, v);
            vk[k] = fmaxf(fmaf(sv, v, tv), 0.f);
            float lg = w2v * a;
#pragma unroll
            for (int off = 32; off >= 1; off >>= 1) lg += __shfl_xor(lg, off, 64);
            ek[k] = lg + b2v;
        }
    }
    float mx = ek[0];
#pragma unroll
    for (int k = 1; k < 16; k++) mx = fmaxf(mx, ek[k]);
    float ssum = 0.f;
#pragma unroll
    for (int k = 0; k < 16; k++) { float e = __expf(ek[k] - mx); ek[k] = e; ssum += e; }
    float acc = 0.f;
#pragma unroll
    for (int k = 0; k < 16; k++) acc = fmaf(ek[k], vk[k], acc);
    float outv = acc / ssum;

    lds_out[wl][lane] = outv;
    __syncthreads();
    float op = bov;
    for (int c = 0; c < 64; c++)
        op = fmaf(pwoT[c * 64 + lane], lds_out[wl][c], op);
    opre[(size_t)orig * 64 + lane] = op;
    ro[wl][lane] = op; ro2[wl][lane] = op * op;
    __syncthreads();
    if (wl == 0) {
        float s = ro[0][lane] + ro[1][lane] + ro[2][lane] + ro[3][lane];
        atomicAdd(&stats[256 + lane], s);
    } else if (wl == 1) {
        float s = ro2[0][lane] + ro2[1][lane] + ro2[2][lane] + ro2[3][lane];
        atomicAdd(&stats[320 + lane], s);
    }
}

// Final: BN(o)+relu + residual feats, transpose [B,N,C]->[B,C,N]
__global__ __launch_bounds__(256) void k_final(
    const float* __restrict__ opre, const float* __restrict__ stats,
    const float* __restrict__ go, const float* __restrict__ beo,
    const float* __restrict__ feats, float* __restrict__ out)
{
    __shared__ float tile[64][65];
    int t = threadIdx.x;
    int blk = blockIdx.x;
    int b = blk >> 7, n0 = (blk & 127) << 6;
#pragma unroll
    for (int i = 0; i < 16; i++) {
        int e = t + i * 256;
        int r = e >> 6, c = e & 63;
        tile[r][c] = opre[((size_t)((b << 13) + n0 + r)) * 64 + c];
    }
    __syncthreads();
    const float invM = 1.f / 32768.f;
    int lane = t & 63, wv = t >> 6;
#pragma unroll
    for (int i = 0; i < 16; i++) {
        int c = wv * 16 + i;
        float om = stats[256 + c] * invM, oq = stats[320 + c] * invM;
        float so = go[c] * rsqrtf(oq - om * om + EPSBN);
        float to = beo[c] - so * om;
        float val = fmaxf(fmaf(so, tile[lane][c], to), 0.f);
        size_t oix = ((size_t)b * 64 + c) * NN + n0 + lane;
        out[oix] = val + feats[oix];
    }
}

extern "C" void kernel_launch(void* const* d_in, const int* in_sizes, int n_in,
                              void* d_out, int out_size, void* d_ws, size_t ws_size,
                              hipStream_t stream)
{
    const float* xyz  = (const float*)d_in[0];
    const float* feats= (const float*)d_in[1];
    const float* W1   = (const float*)d_in[2];
    const float* b1   = (const float*)d_in[3];
    const float* g1   = (const float*)d_in[4];
    const float* be1  = (const float*)d_in[5];
    const float* W2   = (const float*)d_in[6];
    const float* b2   = (const float*)d_in[7];
    const float* Wv   = (const float*)d_in[8];
    const float* bv   = (const float*)d_in[9];
    const float* gv   = (const float*)d_in[10];
    const float* bev  = (const float*)d_in[11];
    const float* Wo   = (const float*)d_in[12];
    const float* bo   = (const float*)d_in[13];
    const float* go   = (const float*)d_in[14];
    const float* beo  = (const float*)d_in[15];

    float* ws = (float*)d_ws;
    float* xyzw  = ws + OFF_XYZW;
    float* pw1aT = ws + OFF_PW1AT;
    float* pw1bT = ws + OFF_PW1BT;
    float* pwvaT = ws + OFF_PWVAT;
    float* pwoT  = ws + OFF_PWOT;
    float* relw  = ws + OFF_RELW;
    float* stats = ws + OFF_STATS;
    int*   idx   = (int*)(ws + OFF_IDX);
    int*   pip   = (int*)(ws + OFF_PIP);
    float4* sx4  = (float4*)(ws + OFF_SX4);
    int*   sid   = (int*)(ws + OFF_SID);
    int*   hist  = (int*)(ws + OFF_HIST);
    float4* bbmn = (float4*)(ws + OFF_BB);
    float4* bbmx = (float4*)(ws + OFF_BB + 512);
    int*   rank  = (int*)(ws + OFF_RANK);
    float* F1    = ws + OFF_F1;
    float* F2    = ws + OFF_F2;
    float* FV    = ws + OFF_FV;
    float* opre  = ws + OFF_OPRE;   // aliases pip (dead after k_refine)

    k_zero<<<1, 256, 0, stream>>>(hist);
    k_prep<<<129, 256, 0, stream>>>(xyz, W1, Wv, Wo, xyzw, hist,
                                    pw1aT, pw1bT, pwvaT, pwoT, relw, stats);
    k_scan<<<4, 256, 0, stream>>>(hist);
    k_scatter<<<128, 256, 0, stream>>>((const float4*)xyzw, hist, sx4, sid, rank);
    k_bbox<<<128, 256, 0, stream>>>((const float4*)sx4, bbmn, bbmx);
    k_F<<<512, 256, 0, stream>>>(feats, b1, bv, pw1aT, pw1bT, pwvaT, rank, F1, F2, FV);
    k_knn<<<8192, 256, 0, stream>>>((const float4*)sx4, bbmn, bbmx, pip);
    k_refine<<<128, 256, 0, stream>>>((const float4*)sx4, sid, pip, idx);
    k_hv<<<2048, 256, 0, stream>>>((const float4*)sx4, idx, F1, F2, FV, relw, stats);
    k_attn<<<8192, 256, 0, stream>>>((const float4*)sx4, sid, idx, F1, F2, FV, relw, stats,
                                     g1, be1, W2, b2, gv, bev, pwoT, bo, opre);
    k_final<<<512, 256, 0, stream>>>(opre, stats, go, beo, feats, (float*)d_out);
}

// Round 9
// 398.351 us; speedup vs baseline: 2.9565x; 1.4555x over previous
//
#include <hip/hip_runtime.h>
#include <math.h>

// Problem constants
#define BB 4
#define NN 8192
#define CC 64
#define KK 16
#define HH 64
#define NPTS (BB*NN)   // 32768
#define EPSBN 1e-5f
#define NCAND 32       // fp32 prefilter keeps top-32; fp64 refine picks 16
#define NCELL 4096     // 16^3 Morton cells
#define NCHUNK 32      // 256-point chunks per batch

// ---------------- ws layout (float offsets) ----------------
#define OFF_XYZW  0
#define OFF_PW1AT 131072
#define OFF_PW1BT 135168
#define OFF_PWVAT 139264
#define OFF_PWOT  143360
#define OFF_RELW  147456
#define OFF_STATS 147840
#define OFF_IDX   148224      // idx: 32768*16 ints (SORTED-space neighbor ids)
#define OFF_PIP   672512      // pip: 32768*32 ints (dead after k_refine)
#define OFF_OUTV  672512      // OUTV aliases PIP: [32768][64] sorted attention output
#define OFF_SX4   2769664     // sorted xyzw [4][8192] float4
#define OFF_SID   2900736     // sorted->orig ids [4][8192] int
#define OFF_HIST  2933504     // [4][4096] int
#define OFF_BB    2949888     // bbmin[128] f4 + bbmax[128] f4
#define OFF_RANK  2950912     // orig->sorted rank [4][8192] int
#define OFF_PH    2983680     // k_hv block partials [2048][256]
#define OFF_PO    3507968     // k_o block partials [512][128]
#define OFF_F1    4866816     // SORTED layout (dead after k_attn)
#define OFF_OPRE  4866816     // OPRE aliases F1: [32768][64] original layout
#define OFF_F2    6963968     // SORTED layout
#define OFF_FV    9061120     // SORTED layout

__device__ __forceinline__ int morton_cell(float x, float y, float z) {
    int cx = (int)floorf((x + 4.f) * 2.f);
    int cy = (int)floorf((y + 4.f) * 2.f);
    int cz = (int)floorf((z + 4.f) * 2.f);
    cx = cx < 0 ? 0 : (cx > 15 ? 15 : cx);
    cy = cy < 0 ? 0 : (cy > 15 ? 15 : cy);
    cz = cz < 0 ? 0 : (cz > 15 ? 15 : cz);
    int ex = (cx & 1) | ((cx & 2) << 2) | ((cx & 4) << 4) | ((cx & 8) << 6);
    int ey = (cy & 1) | ((cy & 2) << 2) | ((cy & 4) << 4) | ((cy & 8) << 6);
    int ez = (cz & 1) | ((cz & 2) << 2) | ((cz & 4) << 4) | ((cz & 8) << 6);
    return ex | (ey << 1) | (ez << 2);
}

__device__ __forceinline__ float distf(float4 me, float jx, float jy, float jz, float jw) {
    float dot = fmaf(me.z, jz, fmaf(me.y, jy, me.x * jx));
    return fmaf(-2.f, dot, me.w) + jw;
}

__device__ __forceinline__ float mind2(float4 me, float4 bmin, float4 bmax) {
    float dx = fmaxf(fmaxf(bmin.x - me.x, me.x - bmax.x), 0.f);
    float dy = fmaxf(fmaxf(bmin.y - me.y, me.y - bmax.y), 0.f);
    float dz = fmaxf(fmaxf(bmin.z - me.z, me.z - bmax.z), 0.f);
    return fmaf(dx, dx, fmaf(dy, dy, dz * dz));
}

__global__ __launch_bounds__(256) void k_zero(int* __restrict__ hist) {
    int t = threadIdx.x;
    for (int i = t; i < BB * NCELL; i += 256) hist[i] = 0;
}

__global__ __launch_bounds__(256) void k_prep(
    const float* __restrict__ xyz, const float* __restrict__ W1,
    const float* __restrict__ Wv, const float* __restrict__ Wo,
    float* __restrict__ xyzw, int* __restrict__ hist,
    float* __restrict__ pw1aT, float* __restrict__ pw1bT,
    float* __restrict__ pwvaT, float* __restrict__ pwoT, float* __restrict__ relw,
    float* __restrict__ stats)
{
    int t = threadIdx.x;
    int bid = blockIdx.x;
    if (bid < 128) {
        int pt = bid * 256 + t;
        int b = pt >> 13, n = pt & 8191;
        const float* xb = xyz + (size_t)b * 3 * NN;
        float x = xb[n], y = xb[NN + n], z = xb[2 * NN + n];
        float sq = __fadd_rn(__fadd_rn(__fmul_rn(x, x), __fmul_rn(y, y)), __fmul_rn(z, z));
        ((float4*)xyzw)[pt] = make_float4(x, y, z, sq);
        atomicAdd(&hist[b * NCELL + morton_cell(x, y, z)], 1);
    } else {
        for (int e = t; e < 4096; e += 256) {
            int c = e >> 6, o = e & 63;
            pw1aT[e] = W1[o * 131 + c];
            pw1bT[e] = W1[o * 131 + 64 + c];
            pwvaT[e] = Wv[o * 67 + c];
            pwoT[e]  = Wo[o * 64 + c];
        }
        for (int e = t; e < 384; e += 256) {
            int d = e >> 6, o = e & 63;
            relw[e] = (d < 3) ? W1[o * 131 + 128 + d] : Wv[o * 67 + 64 + (d - 3)];
            stats[e] = 0.0f;
        }
    }
}

// Exclusive scan of per-batch 4096-bin histogram (in place), one block per batch.
__global__ __launch_bounds__(256) void k_scan(int* __restrict__ hist) {
    __shared__ int part[256];
    int b = blockIdx.x, t = threadIdx.x;
    int* h = hist + b * NCELL;
    int loc[16]; int s = 0;
#pragma unroll
    for (int i = 0; i < 16; i++) { loc[i] = h[t * 16 + i]; s += loc[i]; }
    part[t] = s;
    __syncthreads();
    for (int off = 1; off < 256; off <<= 1) {
        int v = (t >= off) ? part[t - off] : 0;
        __syncthreads();
        part[t] += v;
        __syncthreads();
    }
    int run = (t > 0) ? part[t - 1] : 0;
#pragma unroll
    for (int i = 0; i < 16; i++) { int c = loc[i]; h[t * 16 + i] = run; run += c; }
}

__global__ __launch_bounds__(256) void k_scatter(
    const float4* __restrict__ xyzw, int* __restrict__ off,
    float4* __restrict__ sx4, int* __restrict__ sid, int* __restrict__ rank)
{
    int pt = blockIdx.x * 256 + threadIdx.x;
    int b = pt >> 13, n = pt & 8191;
    float4 p = xyzw[pt];
    int cell = morton_cell(p.x, p.y, p.z);
    int dst = atomicAdd(&off[b * NCELL + cell], 1);
    sx4[(b << 13) + dst] = p;
    sid[(b << 13) + dst] = n;
    rank[pt] = dst;
}

// Per-chunk bbox over 256 sorted points. block = chunk (0..127 global).
__global__ __launch_bounds__(256) void k_bbox(
    const float4* __restrict__ sx4, float4* __restrict__ bbmin, float4* __restrict__ bbmax)
{
    __shared__ float smn[4][3], smx[4][3];
    int ch = blockIdx.x, t = threadIdx.x, lane = t & 63, wl = t >> 6;
    float4 p = sx4[ch * 256 + t];
    float mnx = p.x, mny = p.y, mnz = p.z, mxx = p.x, mxy = p.y, mxz = p.z;
#pragma unroll
    for (int o = 32; o >= 1; o >>= 1) {
        mnx = fminf(mnx, __shfl_xor(mnx, o, 64)); mxx = fmaxf(mxx, __shfl_xor(mxx, o, 64));
        mny = fminf(mny, __shfl_xor(mny, o, 64)); mxy = fmaxf(mxy, __shfl_xor(mxy, o, 64));
        mnz = fminf(mnz, __shfl_xor(mnz, o, 64)); mxz = fmaxf(mxz, __shfl_xor(mxz, o, 64));
    }
    if (lane == 0) { smn[wl][0]=mnx; smn[wl][1]=mny; smn[wl][2]=mnz;
                     smx[wl][0]=mxx; smx[wl][1]=mxy; smx[wl][2]=mxz; }
    __syncthreads();
    if (t == 0) {
        float a0=smn[0][0], a1=smn[0][1], a2=smn[0][2];
        float b0=smx[0][0], b1=smx[0][1], b2=smx[0][2];
        for (int w = 1; w < 4; w++) {
            a0=fminf(a0,smn[w][0]); a1=fminf(a1,smn[w][1]); a2=fminf(a2,smn[w][2]);
            b0=fmaxf(b0,smx[w][0]); b1=fmaxf(b1,smx[w][1]); b2=fmaxf(b2,smx[w][2]);
        }
        bbmin[ch] = make_float4(a0,a1,a2,0.f);
        bbmax[ch] = make_float4(b0,b1,b2,0.f);
    }
}

// Wave-cooperative KNN with warm-start window sort + bbox chunk pruning.
__global__ __launch_bounds__(256) void k_knn(
    const float4* __restrict__ sx4,
    const float4* __restrict__ bbmin, const float4* __restrict__ bbmax,
    int* __restrict__ pip)
{
    __shared__ float lx[256], ly[256], lz[256], lw[256];
    __shared__ unsigned int wmask[4];
    int t = threadIdx.x, lane = t & 63, wl = t >> 6;
    int gq = blockIdx.x * 4 + wl;
    int b = __builtin_amdgcn_readfirstlane(gq >> 13);
    int qs = gq & 8191;
    const float4* sb = sx4 + ((size_t)b << 13);
    float4 me = sb[qs];                       // wave-uniform
    const float INF = 3.402823466e38f;

    // phase 1: sort the 64-point positional window (spatially local -> warm tau)
    int ws0 = qs - 32; ws0 = ws0 < 0 ? 0 : (ws0 > (NN - 64) ? (NN - 64) : ws0);
    float4 cp = sb[ws0 + lane];
    int cid = ws0 + lane;                     // sorted-space id
    float d = distf(me, cp.x, cp.y, cp.z, cp.w);
#pragma unroll
    for (int k2 = 2; k2 <= 64; k2 <<= 1) {
#pragma unroll
        for (int j2 = k2 >> 1; j2 >= 1; j2 >>= 1) {
            float od = __shfl_xor(d, j2, 64);
            int   oi = __shfl_xor(cid, j2, 64);
            bool up = ((lane & k2) == 0);
            bool lower = ((lane & j2) == 0);
            bool wantMin = (lower == up);
            bool to = wantMin ? (od < d) : (od > d);
            d = to ? od : d; cid = to ? oi : cid;
        }
    }
    bool lt32 = (lane < 32);
    float val = lt32 ? d : INF;
    int vid = cid;
    float tau = __int_as_float(__builtin_amdgcn_readlane(__float_as_int(val), 31));

    // phase 2a: chunk mask vs warm tau
    unsigned int m32 = 0;
    for (int c = 0; c < NCHUNK; c++) {
        float md = mind2(me, bbmin[b * NCHUNK + c], bbmax[b * NCHUNK + c]);
        if (md <= tau * 1.0001f + 1e-5f) m32 |= (1u << c);
    }
    if (lane == 0) wmask[wl] = m32;
    __syncthreads();
    unsigned int bm = wmask[0] | wmask[1] | wmask[2] | wmask[3];  // block-uniform

    // phase 2b: scan surviving chunks (window positions excluded -> no dups)
    while (bm) {
        int c = __builtin_ctz(bm); bm &= bm - 1;
        __syncthreads();
        {
            float4 p = sb[c * 256 + t];
            lx[t] = p.x; ly[t] = p.y; lz[t] = p.z; lw[t] = p.w;
        }
        __syncthreads();
        float md = mind2(me, bbmin[b * NCHUNK + c], bbmax[b * NCHUNK + c]);
        if (md <= tau * 1.0001f + 1e-5f) {
#pragma unroll 2
            for (int s = 0; s < 4; s++) {
                int ci = s * 64 + lane;
                int pos = c * 256 + ci;
                float dd = distf(me, lx[ci], ly[ci], lz[ci], lw[ci]);
                bool inwin = (pos >= ws0) && (pos < ws0 + 64);
                dd = inwin ? INF : dd;
                unsigned long long m = __ballot(dd < tau);
                while (m) {
                    int hl = __builtin_ctzll(m); m &= m - 1;
                    float dn = __int_as_float(
                        __builtin_amdgcn_readlane(__float_as_int(dd), hl));
                    int jn = c * 256 + s * 64 + hl;   // sorted-space id (scalar)
                    unsigned long long bl = __ballot(val < dn);
                    int pos2 = __popcll(bl);
                    float sv = __shfl_up(val, 1, 64);
                    int   sj = __shfl_up(vid, 1, 64);
                    float nv = (lane > pos2) ? sv : val; nv = (lane == pos2) ? dn : nv;
                    int   nj = (lane > pos2) ? sj : vid; nj = (lane == pos2) ? jn : nj;
                    val = lt32 ? nv : val;
                    vid = lt32 ? nj : vid;
                    tau = __int_as_float(__builtin_amdgcn_readlane(__float_as_int(val), 31));
                }
            }
        }
    }
    if (lt32) pip[(size_t)gq * NCAND + lane] = vid;
}

// Exact refinement in SORTED space: fp64 distances for 32 candidates,
// top-16 by (d, ORIGINAL index). Outputs sorted-space ids.
__global__ __launch_bounds__(256) void k_refine(
    const float4* __restrict__ sx4, const int* __restrict__ sid,
    const int* __restrict__ pip, int* __restrict__ idx)
{
    int gq = blockIdx.x * 256 + threadIdx.x;
    int b = gq >> 13;
    const float4* sb = sx4 + ((size_t)b << 13);
    const int* ib = sid + ((size_t)b << 13);
    float4 mef = sb[gq & 8191];
    double mx = (double)mef.x, my = (double)mef.y, mz = (double)mef.z;
    double msq = (mx * mx + my * my) + mz * mz;
    double bd[16]; int bi[16]; int bo[16];
#pragma unroll
    for (int s = 0; s < 16; s++) { bd[s] = 1e300; bi[s] = 0; bo[s] = 0x7fffffff; }
    for (int c = 0; c < NCAND; c++) {
        int j = pip[(size_t)gq * NCAND + c];
        float4 cj = sb[j];
        int oj = ib[j];
        double jx = (double)cj.x, jy = (double)cj.y, jz = (double)cj.z;
        double dot = (mx * jx + my * jy) + mz * jz;
        double sqj = (jx * jx + jy * jy) + jz * jz;
        double dd = (-2.0 * dot + msq) + sqj;
        if (dd < bd[15] || (dd == bd[15] && oj < bo[15])) {
            double pd_ = dd; int pi_ = j; int po_ = oj;
#pragma unroll
            for (int s = 15; s >= 1; s--) {
                bool cc = (pd_ < bd[s - 1]) || (pd_ == bd[s - 1] && po_ < bo[s - 1]);
                double nd = cc ? bd[s - 1] : pd_;  int ni = cc ? bi[s - 1] : pi_;  int no = cc ? bo[s - 1] : po_;
                double npd = cc ? pd_ : bd[s - 1]; int npi = cc ? pi_ : bi[s - 1]; int npo = cc ? po_ : bo[s - 1];
                bd[s] = nd; bi[s] = ni; bo[s] = no; pd_ = npd; pi_ = npi; po_ = npo;
            }
            bd[0] = pd_; bi[0] = pi_; bo[0] = po_;
        }
    }
#pragma unroll
    for (int s = 0; s < 16; s++) idx[(size_t)gq * 16 + s] = bi[s];
}

// Per-point GEMVs, output scattered to SORTED layout via rank.
__global__ __launch_bounds__(256) void k_F(
    const float* __restrict__ feats, const float* __restrict__ b1, const float* __restrict__ bv,
    const float* __restrict__ pw1aT, const float* __restrict__ pw1bT, const float* __restrict__ pwvaT,
    const int* __restrict__ rank,
    float* __restrict__ F1, float* __restrict__ F2, float* __restrict__ FV)
{
    int t = threadIdx.x;
    int lane = t & 63;
    int wave = t >> 6;
    int pt0 = blockIdx.x * 64 + wave * 16;
    int b   = __builtin_amdgcn_readfirstlane(pt0 >> 13);
    int n0  = __builtin_amdgcn_readfirstlane(pt0 & 8191);
    const float* fb = feats + (size_t)b * CC * NN;
    float accA[16], accB[16], accV[16];
    float bb1 = b1[lane], bbv = bv[lane];
#pragma unroll
    for (int p = 0; p < 16; p++) { accA[p] = bb1; accB[p] = 0.f; accV[p] = bbv; }
    for (int c = 0; c < 64; c++) {
        float wA = pw1aT[c * 64 + lane];
        float wB = pw1bT[c * 64 + lane];
        float wV = pwvaT[c * 64 + lane];
        const float* fr = fb + (size_t)c * NN + n0;
#pragma unroll
        for (int p = 0; p < 16; p++) {
            float f = fr[p];
            accA[p] = fmaf(wA, f, accA[p]);
            accB[p] = fmaf(wB, f, accB[p]);
            accV[p] = fmaf(wV, f, accV[p]);
        }
    }
#pragma unroll
    for (int p = 0; p < 16; p++) {
        int dst = (b << 13) + rank[pt0 + p];     // wave-uniform scalar
        F1[(size_t)dst * 64 + lane] = accA[p];
        F2[(size_t)dst * 64 + lane] = accB[p];
        FV[(size_t)dst * 64 + lane] = accV[p];
    }
}

// BN stats pass. XCD-swizzled; block partials to PH (NO contended atomics).
__global__ __launch_bounds__(256) void k_hv(
    const float4* __restrict__ sx4, const int* __restrict__ idx,
    const float* __restrict__ F1, const float* __restrict__ F2, const float* __restrict__ FV,
    const float* __restrict__ relw, float* __restrict__ ph)
{
    __shared__ float red[4][4][64];
    int t = threadIdx.x;
    int lane = t & 63;
    int wl = t >> 6;
    int bx = blockIdx.x;                       // 2048 blocks
    int vb = (bx & 7) * 256 + (bx >> 3);       // XCD-aware swizzle
    float rw0 = relw[0 * 64 + lane], rw1 = relw[1 * 64 + lane], rw2 = relw[2 * 64 + lane];
    float rw3 = relw[3 * 64 + lane], rw4 = relw[4 * 64 + lane], rw5 = relw[5 * 64 + lane];
    float sh = 0.f, sh2 = 0.f, sv = 0.f, sv2 = 0.f;
    for (int i = 0; i < 4; i++) {
        int gq = __builtin_amdgcn_readfirstlane(vb * 16 + wl * 4 + i);  // contiguous
        int b = gq >> 13;
        const float4* sb = sx4 + ((size_t)b << 13);
        float4 me = sb[gq & 8191];
        float F1v = F1[(size_t)gq * 64 + lane];
        const int* ip = idx + (size_t)gq * 16;
#pragma unroll
        for (int kb = 0; kb < 2; kb++) {
            float4 cjA[8]; float f2A[8], fvA[8];
#pragma unroll
            for (int j = 0; j < 8; j++) {
                int gl = ip[kb * 8 + j];
                cjA[j] = sb[gl];
                size_t go = (size_t)((b << 13) + gl) * 64 + lane;
                f2A[j] = F2[go];
                fvA[j] = FV[go];
            }
#pragma unroll
            for (int j = 0; j < 8; j++) {
                float rx = cjA[j].x - me.x, ry = cjA[j].y - me.y, rz = cjA[j].z - me.z;
                float h = F1v + f2A[j];
                h = fmaf(rw0, rx, h); h = fmaf(rw1, ry, h); h = fmaf(rw2, rz, h);
                float v = fvA[j];
                v = fmaf(rw3, rx, v); v = fmaf(rw4, ry, v); v = fmaf(rw5, rz, v);
                sh += h; sh2 = fmaf(h, h, sh2);
                sv += v; sv2 = fmaf(v, v, sv2);
            }
        }
    }
    red[0][wl][lane] = sh; red[1][wl][lane] = sh2;
    red[2][wl][lane] = sv; red[3][wl][lane] = sv2;
    __syncthreads();
    float s = red[wl][0][lane] + red[wl][1][lane] + red[wl][2][lane] + red[wl][3][lane];
    ph[(size_t)bx * 256 + wl * 64 + lane] = s;     // plain store, no contention
}

// Reduce PH -> stats[0..255]. 32 blocks x 64 rows each; light atomics (32/addr).
__global__ __launch_bounds__(256) void k_red1(
    const float* __restrict__ ph, float* __restrict__ stats)
{
    int t = threadIdx.x, p = blockIdx.x;
    float acc = 0.f;
    for (int i = 0; i < 64; i++)
        acc += ph[(size_t)(p * 64 + i) * 256 + t];
    atomicAdd(&stats[t], acc);
}

// Attention in SORTED space, XCD-swizzled. Barrier-free, atomic-free, LDS-free:
// gather -> BN+relu -> logits -> softmax -> weighted sum -> store outv row.
__global__ __launch_bounds__(256) void k_attn(
    const float4* __restrict__ sx4,
    const int* __restrict__ idx,
    const float* __restrict__ F1, const float* __restrict__ F2, const float* __restrict__ FV,
    const float* __restrict__ relw, const float* __restrict__ stats,
    const float* __restrict__ g1, const float* __restrict__ be1,
    const float* __restrict__ W2, const float* __restrict__ b2,
    const float* __restrict__ gv, const float* __restrict__ bev,
    float* __restrict__ outv)
{
    int t = threadIdx.x;
    int lane = t & 63;
    int wl = t >> 6;
    int bx = blockIdx.x;                      // 8192 blocks
    int vb = (bx & 7) * 1024 + (bx >> 3);     // XCD-aware swizzle
    int gq = vb * 4 + wl;                     // sorted-global query
    const float invM = 1.f / 524288.f;
    float hm = stats[lane] * invM, hq = stats[64 + lane] * invM;
    float s1 = g1[lane] * rsqrtf(hq - hm * hm + EPSBN);
    float t1 = be1[lane] - s1 * hm;
    float vm = stats[128 + lane] * invM, vq = stats[192 + lane] * invM;
    float sv = gv[lane] * rsqrtf(vq - vm * vm + EPSBN);
    float tv = bev[lane] - sv * vm;
    float rw0 = relw[0 * 64 + lane], rw1 = relw[1 * 64 + lane], rw2 = relw[2 * 64 + lane];
    float rw3 = relw[3 * 64 + lane], rw4 = relw[4 * 64 + lane], rw5 = relw[5 * 64 + lane];
    float w2v = W2[lane];
    float b2v = b2[0];

    int b = __builtin_amdgcn_readfirstlane(gq >> 13);
    const float4* sb = sx4 + ((size_t)b << 13);
    float4 me = sb[gq & 8191];
    float F1v = F1[(size_t)gq * 64 + lane];
    const int* ip = idx + (size_t)gq * 16;
    float ek[16], vk[16];
#pragma unroll
    for (int kb = 0; kb < 2; kb++) {
        float4 cjA[8]; float f2A[8], fvA[8];
#pragma unroll
        for (int j = 0; j < 8; j++) {
            int gl = ip[kb * 8 + j];
            cjA[j] = sb[gl];
            size_t go = (size_t)((b << 13) + gl) * 64 + lane;
            f2A[j] = F2[go];
            fvA[j] = FV[go];
        }
#pragma unroll
        for (int j = 0; j < 8; j++) {
            int k = kb * 8 + j;
            float rx = cjA[j].x - me.x, ry = cjA[j].y - me.y, rz = cjA[j].z - me.z;
            float h = F1v + f2A[j];
            h = fmaf(rw0, rx, h); h = fmaf(rw1, ry, h); h = fmaf(rw2, rz, h);
            float a = fmaxf(fmaf(s1, h, t1), 0.f);
            float v = fvA[j];
            v = fmaf(rw3, rx, v); v = fmaf(rw4, ry, v); v = fmaf(rw5, rz, v);
            vk[k] = fmaxf(fmaf(sv, v, tv), 0.f);
            float lg = w2v * a;
#pragma unroll
            for (int off = 32; off >= 1; off >>= 1) lg += __shfl_xor(lg, off, 64);
            ek[k] = lg + b2v;
        }
    }
    float mx = ek[0];
#pragma unroll
    for (int k = 1; k < 16; k++) mx = fmaxf(mx, ek[k]);
    float ssum = 0.f;
#pragma unroll
    for (int k = 0; k < 16; k++) { float e = __expf(ek[k] - mx); ek[k] = e; ssum += e; }
    float acc = 0.f;
#pragma unroll
    for (int k = 0; k < 16; k++) acc = fmaf(ek[k], vk[k], acc);
    outv[(size_t)gq * 64 + lane] = acc / ssum;
}

// Wo matvec + o-stats: out rows (sorted) -> o_pre rows (ORIGINAL layout) + PO partials.
__global__ __launch_bounds__(256) void k_o(
    const float* __restrict__ outv, const float* __restrict__ pwoT,
    const float* __restrict__ bo, const int* __restrict__ sid,
    float* __restrict__ opre, float* __restrict__ po)
{
    __shared__ float red[2][4][64];
    int t = threadIdx.x;
    int lane = t & 63;
    int wl = t >> 6;
    int gq0 = blockIdx.x * 64 + wl * 16;       // 16 sorted points per wave
    int b = __builtin_amdgcn_readfirstlane(gq0 >> 13);
    float acc[16];
    float bov = bo[lane];
#pragma unroll
    for (int p = 0; p < 16; p++) acc[p] = bov;
    for (int c = 0; c < 64; c++) {
        float w = pwoT[c * 64 + lane];
        const float* orow = outv + (size_t)gq0 * 64 + c;
#pragma unroll
        for (int p = 0; p < 16; p++)
            acc[p] = fmaf(w, orow[p * 64], acc[p]);
    }
    float so = 0.f, so2 = 0.f;
#pragma unroll
    for (int p = 0; p < 16; p++) {
        int orig = (b << 13) + sid[gq0 + p];   // wave-uniform scalar
        opre[(size_t)orig * 64 + lane] = acc[p];
        so += acc[p]; so2 = fmaf(acc[p], acc[p], so2);
    }
    red[0][wl][lane] = so; red[1][wl][lane] = so2;
    __syncthreads();
    if (wl < 2) {
        float s = red[wl][0][lane] + red[wl][1][lane] + red[wl][2][lane] + red[wl][3][lane];
        po[(size_t)blockIdx.x * 128 + wl * 64 + lane] = s;
    }
}

// Reduce PO -> stats[256..383]. 8 blocks x 64 rows; light atomics.
__global__ __launch_bounds__(256) void k_red2(
    const float* __restrict__ po, float* __restrict__ stats)
{
    int t = threadIdx.x, p = blockIdx.x;
    if (t < 128) {
        float acc = 0.f;
        for (int i = 0; i < 64; i++)
            acc += po[(size_t)(p * 64 + i) * 128 + t];
        atomicAdd(&stats[256 + t], acc);
    }
}

// Final: BN(o)+relu + residual feats, transpose [B,N,C]->[B,C,N]
__global__ __launch_bounds__(256) void k_final(
    const float* __restrict__ opre, const float* __restrict__ stats,
    const float* __restrict__ go, const float* __restrict__ beo,
    const float* __restrict__ feats, float* __restrict__ out)
{
    __shared__ float tile[64][65];
    int t = threadIdx.x;
    int blk = blockIdx.x;
    int b = blk >> 7, n0 = (blk & 127) << 6;
#pragma unroll
    for (int i = 0; i < 16; i++) {
        int e = t + i * 256;
        int r = e >> 6, c = e & 63;
        tile[r][c] = opre[((size_t)((b << 13) + n0 + r)) * 64 + c];
    }
    __syncthreads();
    const float invM = 1.f / 32768.f;
    int lane = t & 63, wv = t >> 6;
#pragma unroll
    for (int i = 0; i < 16; i++) {
        int c = wv * 16 + i;
        float om = stats[256 + c] * invM, oq = stats[320 + c] * invM;
        float so = go[c] * rsqrtf(oq - om * om + EPSBN);
        float to = beo[c] - so * om;
        float val = fmaxf(fmaf(so, tile[lane][c], to), 0.f);
        size_t oix = ((size_t)b * 64 + c) * NN + n0 + lane;
        out[oix] = val + feats[oix];
    }
}

extern "C" void kernel_launch(void* const* d_in, const int* in_sizes, int n_in,
                              void* d_out, int out_size, void* d_ws, size_t ws_size,
                              hipStream_t stream)
{
    const float* xyz  = (const float*)d_in[0];
    const float* feats= (const float*)d_in[1];
    const float* W1   = (const float*)d_in[2];
    const float* b1   = (const float*)d_in[3];
    const float* g1   = (const float*)d_in[4];
    const float* be1  = (const float*)d_in[5];
    const float* W2   = (const float*)d_in[6];
    const float* b2   = (const float*)d_in[7];
    const float* Wv   = (const float*)d_in[8];
    const float* bv   = (const float*)d_in[9];
    const float* gv   = (const float*)d_in[10];
    const float* bev  = (const float*)d_in[11];
    const float* Wo   = (const float*)d_in[12];
    const float* bo   = (const float*)d_in[13];
    const float* go   = (const float*)d_in[14];
    const float* beo  = (const float*)d_in[15];

    float* ws = (float*)d_ws;
    float* xyzw  = ws + OFF_XYZW;
    float* pw1aT = ws + OFF_PW1AT;
    float* pw1bT = ws + OFF_PW1BT;
    float* pwvaT = ws + OFF_PWVAT;
    float* pwoT  = ws + OFF_PWOT;
    float* relw  = ws + OFF_RELW;
    float* stats = ws + OFF_STATS;
    int*   idx   = (int*)(ws + OFF_IDX);
    int*   pip   = (int*)(ws + OFF_PIP);
    float* outv  = ws + OFF_OUTV;   // aliases pip (dead after k_refine)
    float4* sx4  = (float4*)(ws + OFF_SX4);
    int*   sid   = (int*)(ws + OFF_SID);
    int*   hist  = (int*)(ws + OFF_HIST);
    float4* bbmn = (float4*)(ws + OFF_BB);
    float4* bbmx = (float4*)(ws + OFF_BB + 512);
    int*   rank  = (int*)(ws + OFF_RANK);
    float* ph    = ws + OFF_PH;
    float* po    = ws + OFF_PO;
    float* F1    = ws + OFF_F1;
    float* F2    = ws + OFF_F2;
    float* FV    = ws + OFF_FV;
    float* opre  = ws + OFF_OPRE;   // aliases F1 (dead after k_attn)

    k_zero<<<1, 256, 0, stream>>>(hist);
    k_prep<<<129, 256, 0, stream>>>(xyz, W1, Wv, Wo, xyzw, hist,
                                    pw1aT, pw1bT, pwvaT, pwoT, relw, stats);
    k_scan<<<4, 256, 0, stream>>>(hist);
    k_scatter<<<128, 256, 0, stream>>>((const float4*)xyzw, hist, sx4, sid, rank);
    k_bbox<<<128, 256, 0, stream>>>((const float4*)sx4, bbmn, bbmx);
    k_F<<<512, 256, 0, stream>>>(feats, b1, bv, pw1aT, pw1bT, pwvaT, rank, F1, F2, FV);
    k_knn<<<8192, 256, 0, stream>>>((const float4*)sx4, bbmn, bbmx, pip);
    k_refine<<<128, 256, 0, stream>>>((const float4*)sx4, sid, pip, idx);
    k_hv<<<2048, 256, 0, stream>>>((const float4*)sx4, idx, F1, F2, FV, relw, ph);
    k_red1<<<32, 256, 0, stream>>>(ph, stats);
    k_attn<<<8192, 256, 0, stream>>>((const float4*)sx4, idx, F1, F2, FV, relw, stats,
                                     g1, be1, W2, b2, gv, bev, outv);
    k_o<<<512, 256, 0, stream>>>(outv, pwoT, bo, sid, opre, po);
    k_red2<<<8, 256, 0, stream>>>(po, stats);
    k_final<<<512, 256, 0, stream>>>(opre, stats, go, beo, feats, (float*)d_out);
}